// Round 1
// baseline (1018.406 us; speedup 1.0000x reference)
//
#include <hip/hip_runtime.h>
#include <cstdint>
#include <cstddef>

// ---------------- problem constants ----------------
#define BTOK 65536
#define DDIM 256
#define NEXP 16
#define HDIM 256
#define ODIM 256
#define G1N  1024
#define TAU  2e-4
#define AMB_CAP 4096

typedef _Float16 fp16x8 __attribute__((ext_vector_type(8)));
typedef float    f32x4_t __attribute__((ext_vector_type(4)));

__device__ __forceinline__ void async_ld16(const void* g, void* l) {
  __builtin_amdgcn_global_load_lds(
      (const __attribute__((address_space(1))) unsigned int*)g,
      (__attribute__((address_space(3))) unsigned int*)l, 16, 0, 0);
}

// ---------------- weight transpose + f32->f16 hi/lo ----------------
// src fp32 [R][C] (batched via blockIdx.z), dst f16 [C][R] (hi, optional lo)
__global__ __launch_bounds__(256) void k_transpose_cvt(
    const float* __restrict__ src, _Float16* __restrict__ dhi,
    _Float16* __restrict__ dlo, int R, int C) {
  __shared__ float s[32][33];
  int bz = blockIdx.z;
  size_t stride = (size_t)R * C;
  src += (size_t)bz * stride;
  dhi += (size_t)bz * stride;
  if (dlo) dlo += (size_t)bz * stride;
  int c0 = blockIdx.x * 32, r0 = blockIdx.y * 32;
  int tx = threadIdx.x & 31, ty = threadIdx.x >> 5;  // ty 0..7
  for (int k = 0; k < 32; k += 8)
    s[ty + k][tx] = src[(size_t)(r0 + ty + k) * C + c0 + tx];
  __syncthreads();
  for (int k = 0; k < 32; k += 8) {
    float v = s[tx][ty + k];
    _Float16 h = (_Float16)v;
    size_t o = (size_t)(c0 + ty + k) * R + r0 + tx;
    dhi[o] = h;
    if (dlo) dlo[o] = (_Float16)(v - (float)h);
  }
}

// ---------------- x fp32 -> f16 hi/lo ----------------
__global__ __launch_bounds__(256) void k_xcvt(const float* __restrict__ x,
                                              _Float16* __restrict__ xhi,
                                              _Float16* __restrict__ xlo, int n8) {
  int i = blockIdx.x * 256 + threadIdx.x;
  if (i >= n8) return;
  const float4* p = (const float4*)x;
  float4 a = p[(size_t)i * 2], b = p[(size_t)i * 2 + 1];
  float v[8] = {a.x, a.y, a.z, a.w, b.x, b.y, b.z, b.w};
  fp16x8 hv, lv;
#pragma unroll
  for (int j = 0; j < 8; j++) {
    _Float16 h = (_Float16)v[j];
    hv[j] = h;
    lv[j] = (_Float16)(v[j] - (float)h);
  }
  *(fp16x8*)(xhi + (size_t)i * 8) = hv;
  *(fp16x8*)(xlo + (size_t)i * 8) = lv;
}

// ---------------- split-f16 GEMM: C = relu(A @ B^T + bias), hi/lo out ------
// A: [M][K] hi/lo f16 ; B: [N][K] hi/lo f16 (pre-transposed) ; out [M][N] hi/lo
__global__ __launch_bounds__(256) void k_gemm_split(
    const _Float16* __restrict__ Ahi, const _Float16* __restrict__ Alo,
    const _Float16* __restrict__ Bhi, const _Float16* __restrict__ Blo,
    const float* __restrict__ bias,
    _Float16* __restrict__ Chi, _Float16* __restrict__ Clo,
    int M, int N, int K) {
  __shared__ _Float16 sAh[128 * 32], sAl[128 * 32], sBh[128 * 32], sBl[128 * 32];
  const int tid = threadIdx.x;
  const int lane = tid & 63;
  const int wave = tid >> 6;
  const int wr = wave >> 1, wc = wave & 1;
  const int m0 = blockIdx.y * 128, n0 = blockIdx.x * 128;

  f32x4_t zero4 = {0.f, 0.f, 0.f, 0.f};
  f32x4_t acc[4][4];
#pragma unroll
  for (int i = 0; i < 4; i++)
#pragma unroll
    for (int j = 0; j < 4; j++) acc[i][j] = zero4;

  for (int k0 = 0; k0 < K; k0 += 32) {
#pragma unroll
    for (int r = 0; r < 2; r++) {
      int idx = r * 256 + tid;
      int row = idx >> 2, ch = idx & 3;
      int gch = ch ^ (row & 3);
      size_t ga = (size_t)(m0 + row) * K + k0 + gch * 8;
      size_t gb = (size_t)(n0 + row) * K + k0 + gch * 8;
      async_ld16(Ahi + ga, &sAh[idx * 8]);
      async_ld16(Alo + ga, &sAl[idx * 8]);
      async_ld16(Bhi + gb, &sBh[idx * 8]);
      async_ld16(Blo + gb, &sBl[idx * 8]);
    }
    __syncthreads();
    fp16x8 ah[4], al[4], bh[4], bl[4];
    int kc = lane >> 4;
#pragma unroll
    for (int i = 0; i < 4; i++) {
      int ar = wr * 64 + i * 16 + (lane & 15);
      int offa = ar * 32 + ((kc ^ (ar & 3)) << 3);
      ah[i] = *(const fp16x8*)&sAh[offa];
      al[i] = *(const fp16x8*)&sAl[offa];
      int br = wc * 64 + i * 16 + (lane & 15);
      int offb = br * 32 + ((kc ^ (br & 3)) << 3);
      bh[i] = *(const fp16x8*)&sBh[offb];
      bl[i] = *(const fp16x8*)&sBl[offb];
    }
#pragma unroll
    for (int i = 0; i < 4; i++)
#pragma unroll
      for (int j = 0; j < 4; j++) {
        acc[i][j] = __builtin_amdgcn_mfma_f32_16x16x32_f16(ah[i], bh[j], acc[i][j], 0, 0, 0);
        acc[i][j] = __builtin_amdgcn_mfma_f32_16x16x32_f16(ah[i], bl[j], acc[i][j], 0, 0, 0);
        acc[i][j] = __builtin_amdgcn_mfma_f32_16x16x32_f16(al[i], bh[j], acc[i][j], 0, 0, 0);
      }
    __syncthreads();
  }
#pragma unroll
  for (int j = 0; j < 4; j++) {
    int col = n0 + wc * 64 + j * 16 + (lane & 15);
    float bc = bias[col];
#pragma unroll
    for (int i = 0; i < 4; i++)
#pragma unroll
      for (int q = 0; q < 4; q++) {
        int row = m0 + wr * 64 + i * 16 + ((lane >> 4) << 2) + q;
        float v = acc[i][j][q] + bc;
        v = v > 0.f ? v : 0.f;
        _Float16 h = (_Float16)v;
        size_t o = (size_t)row * N + col;
        Chi[o] = h;
        Clo[o] = (_Float16)(v - (float)h);
      }
  }
}

// ---------------- gate layer 3 + softmax + top2 + renorm ----------------
__global__ __launch_bounds__(256) void k_gate3(
    const _Float16* __restrict__ h2hi, const _Float16* __restrict__ h2lo,
    const float* __restrict__ g3, const float* __restrict__ gb3,
    float* __restrict__ pout, int* __restrict__ idx0, int* __restrict__ idx1,
    float* __restrict__ w0, float* __restrict__ w1,
    int* __restrict__ ambCnt, int* __restrict__ ambList) {
  __shared__ _Float16 shh[16 * 256], shl[16 * 256];
  __shared__ float sg3[16][260];
  __shared__ float sgb[16];
  __shared__ double slog[16][17];
  __shared__ int sidx[16][2];
  __shared__ float swv[16][2];
  int tid = threadIdx.x;
  int tokBase = blockIdx.x * 16;
  {
    int t = tid >> 4, c = (tid & 15) * 16;
    size_t g = (size_t)(tokBase + t) * 256 + c;
    *(fp16x8*)&shh[t * 256 + c] = *(const fp16x8*)&h2hi[g];
    *(fp16x8*)&shh[t * 256 + c + 8] = *(const fp16x8*)&h2hi[g + 8];
    *(fp16x8*)&shl[t * 256 + c] = *(const fp16x8*)&h2lo[g];
    *(fp16x8*)&shl[t * 256 + c + 8] = *(const fp16x8*)&h2lo[g + 8];
  }
#pragma unroll
  for (int r = 0; r < 16; r++) {
    int j = r * 256 + tid;
    sg3[j & 15][j >> 4] = g3[j];
  }
  if (tid < 16) sgb[tid] = gb3[tid];
  __syncthreads();
  int t = tid >> 4, e = tid & 15;
  const _Float16* ph = &shh[t * 256];
  const _Float16* pl = &shl[t * 256];
  const float* pg = &sg3[e][0];
  double acc = 0.0;
  for (int k = 0; k < 256; k += 8) {
    fp16x8 hv = *(const fp16x8*)&ph[k];
    fp16x8 lv = *(const fp16x8*)&pl[k];
    float4 ga = *(const float4*)&pg[k];
    float4 gb = *(const float4*)&pg[k + 4];
    float gv[8] = {ga.x, ga.y, ga.z, ga.w, gb.x, gb.y, gb.z, gb.w};
#pragma unroll
    for (int j = 0; j < 8; j++) {
      double a = (double)(float)hv[j] + (double)(float)lv[j];
      acc = fma(a, (double)gv[j], acc);
    }
  }
  acc += (double)sgb[e];
  slog[t][e] = acc;
  __syncthreads();
  if (e == 0) {
    double l[16];
#pragma unroll
    for (int i = 0; i < 16; i++) l[i] = slog[t][i];
    int i1 = 0;
    for (int i = 1; i < 16; i++) if (l[i] > l[i1]) i1 = i;
    int i2 = -1;
    for (int i = 0; i < 16; i++) { if (i == i1) continue; if (i2 < 0 || l[i] > l[i2]) i2 = i; }
    double l3 = -1e300;
    for (int i = 0; i < 16; i++) { if (i == i1 || i == i2) continue; if (l[i] > l3) l3 = l[i]; }
    double lmax = l[i1];
    double S = 0.0;
    for (int i = 0; i < 16; i++) S += exp(l[i] - lmax);
    double p1 = 1.0 / S, p2 = exp(l[i2] - lmax) / S;
    double den = p1 + p2 + 1e-9;
    sidx[t][0] = i1; sidx[t][1] = i2;
    swv[t][0] = (float)(p1 / den); swv[t][1] = (float)(p2 / den);
    if (l[i2] - l3 < TAU) {
      int pos = atomicAdd(ambCnt, 1);
      if (pos < AMB_CAP) ambList[pos] = tokBase + t;
    }
  }
  __syncthreads();
  int i1 = sidx[t][0], i2 = sidx[t][1];
  float pv = (e == i1) ? swv[t][0] : ((e == i2) ? swv[t][1] : 0.f);
  pout[(size_t)(tokBase + t) * 16 + e] = pv;
  if (e == 0) {
    int tok = tokBase + t;
    idx0[tok] = i1; idx1[tok] = i2;
    w0[tok] = swv[t][0]; w1[tok] = swv[t][1];
  }
}

// ---------------- fp64 exact re-resolution of near-tie tokens ----------------
__global__ __launch_bounds__(256) void k_refine(
    const float* __restrict__ x, const float* __restrict__ g1, const float* __restrict__ gb1,
    const float* __restrict__ g2, const float* __restrict__ gb2,
    const float* __restrict__ g3, const float* __restrict__ gb3,
    const int* __restrict__ ambCnt, const int* __restrict__ ambList,
    float* __restrict__ pout, int* __restrict__ idx0, int* __restrict__ idx1,
    float* __restrict__ w0, float* __restrict__ w1) {
  __shared__ double sx[256];
  __shared__ double sh1[1024];
  __shared__ double sh2[256];
  __shared__ double sl[16];
  int tid = threadIdx.x;
  int n = *ambCnt;
  if (n > AMB_CAP) n = AMB_CAP;
  for (int ii = blockIdx.x; ii < n; ii += gridDim.x) {
    int tok = ambList[ii];
    sx[tid] = (double)x[(size_t)tok * 256 + tid];
    __syncthreads();
    for (int r = 0; r < 4; r++) {
      int nn = r * 256 + tid;
      double a = 0.0;
      for (int k = 0; k < 256; k++) a = fma(sx[k], (double)g1[(size_t)k * 1024 + nn], a);
      a += (double)gb1[nn];
      sh1[nn] = a > 0.0 ? a : 0.0;
    }
    __syncthreads();
    {
      double a = 0.0;
      for (int k = 0; k < 1024; k++) a = fma(sh1[k], (double)g2[(size_t)k * 256 + tid], a);
      a += (double)gb2[tid];
      sh2[tid] = a > 0.0 ? a : 0.0;
    }
    __syncthreads();
    if (tid < 16) {
      double a = 0.0;
      for (int k = 0; k < 256; k++) a = fma(sh2[k], (double)g3[k * 16 + tid], a);
      sl[tid] = a + (double)gb3[tid];
    }
    __syncthreads();
    if (tid == 0) {
      double l[16];
      for (int i = 0; i < 16; i++) l[i] = sl[i];
      int i1 = 0;
      for (int i = 1; i < 16; i++) if (l[i] > l[i1]) i1 = i;
      int i2 = -1;
      for (int i = 0; i < 16; i++) { if (i == i1) continue; if (i2 < 0 || l[i] > l[i2]) i2 = i; }
      double lmax = l[i1];
      double S = 0.0;
      for (int i = 0; i < 16; i++) S += exp(l[i] - lmax);
      double p1 = 1.0 / S, p2 = exp(l[i2] - lmax) / S;
      double den = p1 + p2 + 1e-9;
      float fw0 = (float)(p1 / den), fw1 = (float)(p2 / den);
      for (int i = 0; i < 16; i++) pout[(size_t)tok * 16 + i] = 0.f;
      pout[(size_t)tok * 16 + i1] = fw0;
      pout[(size_t)tok * 16 + i2] = fw1;
      idx0[tok] = i1; idx1[tok] = i2;
      w0[tok] = fw0; w1[tok] = fw1;
    }
    __syncthreads();
  }
}

// ---------------- bucket-by-expert: histogram / offsets / scatter ----------
__global__ __launch_bounds__(256) void k_hist(const int* __restrict__ idx0,
                                              const int* __restrict__ idx1,
                                              int* __restrict__ cnt0, int* __restrict__ cnt1) {
  __shared__ int c0[16], c1[16];
  int tid = threadIdx.x;
  if (tid < 16) { c0[tid] = 0; c1[tid] = 0; }
  __syncthreads();
  int b = blockIdx.x * 256 + tid;
  atomicAdd(&c0[idx0[b]], 1);
  atomicAdd(&c1[idx1[b]], 1);
  __syncthreads();
  if (tid < 16) { atomicAdd(&cnt0[tid], c0[tid]); atomicAdd(&cnt1[tid], c1[tid]); }
}

__global__ void k_offsets(const int* __restrict__ cnt0, const int* __restrict__ cnt1,
                          int* off0, int* off1, int* cur0, int* cur1,
                          int* dExp0, int* dRow0, int* dExp1, int* dRow1, int* nTiles) {
  if (threadIdx.x == 0) {
    int tot = 0, nt = 0;
    for (int e = 0; e < 16; e++) {
      off0[e] = tot; cur0[e] = 0;
      int tiles = (cnt0[e] + 127) >> 7;
      for (int ti = 0; ti < tiles; ti++) { dExp0[nt] = e; dRow0[nt] = tot + ti * 128; nt++; }
      tot += tiles * 128;
    }
    nTiles[0] = nt;
    tot = 0; nt = 0;
    for (int e = 0; e < 16; e++) {
      off1[e] = tot; cur1[e] = 0;
      int tiles = (cnt1[e] + 127) >> 7;
      for (int ti = 0; ti < tiles; ti++) { dExp1[nt] = e; dRow1[nt] = tot + ti * 128; nt++; }
      tot += tiles * 128;
    }
    nTiles[1] = nt;
  }
}

__global__ __launch_bounds__(256) void k_scatter(
    const int* __restrict__ idx0, const int* __restrict__ idx1,
    const float* __restrict__ w0, const float* __restrict__ w1,
    const int* __restrict__ off0, const int* __restrict__ off1,
    int* cur0, int* cur1,
    int* __restrict__ tok0, float* __restrict__ wl0,
    int* __restrict__ tok1, float* __restrict__ wl1) {
  __shared__ int c0[16], c1[16], b0[16], b1[16];
  int tid = threadIdx.x;
  if (tid < 16) { c0[tid] = 0; c1[tid] = 0; }
  __syncthreads();
  int b = blockIdx.x * 256 + tid;
  int e0 = idx0[b], e1 = idx1[b];
  int r0 = atomicAdd(&c0[e0], 1);
  int r1 = atomicAdd(&c1[e1], 1);
  __syncthreads();
  if (tid < 16) { b0[tid] = atomicAdd(&cur0[tid], c0[tid]); b1[tid] = atomicAdd(&cur1[tid], c1[tid]); }
  __syncthreads();
  int p0 = off0[e0] + b0[e0] + r0;
  tok0[p0] = b; wl0[p0] = w0[b];
  int p1 = off1[e1] + b1[e1] + r1;
  tok1[p1] = b; wl1[p1] = w1[b];
}

// ---------------- fused 2-layer expert MLP, grouped by expert --------------
// out tile 128 tokens x 256 ; PASSB==0 -> y =, PASSB==1 -> y +=
template <int PASSB>
__global__ __launch_bounds__(512) void k_expert(
    const _Float16* __restrict__ xhi, const float* __restrict__ bias,
    const _Float16* __restrict__ W1T, const float* __restrict__ b1,
    const _Float16* __restrict__ W2T, const float* __restrict__ b2,
    const int* __restrict__ dExp, const int* __restrict__ dRow,
    const int* __restrict__ nT,
    const int* __restrict__ tokL, const float* __restrict__ wL,
    float* __restrict__ y) {
  __shared__ _Float16 sA[128 * 64];
  __shared__ _Float16 sB[256 * 64];
  __shared__ _Float16 sHE[128 * 264];
  __shared__ int sTok[128];
  __shared__ float sW[128];
  int tid = threadIdx.x, lane = tid & 63, wave = tid >> 6;
  int wr = wave >> 2, wc = wave & 3;
  f32x4_t zero4 = {0.f, 0.f, 0.f, 0.f};
  int nt = *nT;
  for (int t = blockIdx.x; t < nt; t += gridDim.x) {
    int e = dExp[t], rowOff = dRow[t];
    if (tid < 128) { sTok[tid] = tokL[rowOff + tid]; sW[tid] = wL[rowOff + tid]; }
    __syncthreads();
    f32x4_t acc[4][4];
#pragma unroll
    for (int i = 0; i < 4; i++)
#pragma unroll
      for (int j = 0; j < 4; j++) acc[i][j] = zero4;
    const _Float16* W1e = W1T + (size_t)e * 65536;
    const _Float16* W2e = W2T + (size_t)e * 65536;
    const float* be = bias + e * 256;
    // ---- phase 1: he = relu((x+bias) @ W1^T) ----
    for (int k0 = 0; k0 < 256; k0 += 64) {
#pragma unroll
      for (int r = 0; r < 2; r++) {
        int idx = r * 512 + tid;
        int row = idx >> 3, ch = idx & 7, gch = ch ^ (row & 7);
        int tok = sTok[row];
        int tk = tok < 0 ? 0 : tok;
        fp16x8 v = *(const fp16x8*)&xhi[(size_t)tk * 256 + k0 + gch * 8];
        const float* bp = &be[k0 + gch * 8];
#pragma unroll
        for (int j = 0; j < 8; j++) v[j] = (_Float16)((float)v[j] + bp[j]);
        *(fp16x8*)&sA[row * 64 + ch * 8] = v;
      }
#pragma unroll
      for (int r = 0; r < 4; r++) {
        int idx = r * 512 + tid;
        int row = idx >> 3, ch = idx & 7, gch = ch ^ (row & 7);
        *(fp16x8*)&sB[row * 64 + ch * 8] =
            *(const fp16x8*)&W1e[(size_t)row * 256 + k0 + gch * 8];
      }
      __syncthreads();
#pragma unroll
      for (int kk = 0; kk < 2; kk++) {
        fp16x8 a[4], bf[4];
        int kcg = kk * 4 + (lane >> 4);
#pragma unroll
        for (int i = 0; i < 4; i++) {
          int ar = wr * 64 + i * 16 + (lane & 15);
          a[i] = *(const fp16x8*)&sA[ar * 64 + (kcg ^ (ar & 7)) * 8];
          int br = wc * 64 + i * 16 + (lane & 15);
          bf[i] = *(const fp16x8*)&sB[br * 64 + (kcg ^ (br & 7)) * 8];
        }
#pragma unroll
        for (int i = 0; i < 4; i++)
#pragma unroll
          for (int j = 0; j < 4; j++)
            acc[i][j] = __builtin_amdgcn_mfma_f32_16x16x32_f16(a[i], bf[j], acc[i][j], 0, 0, 0);
      }
      __syncthreads();
    }
#pragma unroll
    for (int j = 0; j < 4; j++) {
      int col = wc * 64 + j * 16 + (lane & 15);
      float bb = b1[e * 256 + col];
#pragma unroll
      for (int i = 0; i < 4; i++)
#pragma unroll
        for (int q = 0; q < 4; q++) {
          int row = wr * 64 + i * 16 + ((lane >> 4) << 2) + q;
          float v = acc[i][j][q] + bb;
          v = v > 0.f ? v : 0.f;
          sHE[row * 264 + col] = (_Float16)v;
        }
    }
#pragma unroll
    for (int i = 0; i < 4; i++)
#pragma unroll
      for (int j = 0; j < 4; j++) acc[i][j] = zero4;
    __syncthreads();
    // ---- phase 2: out = he @ W2^T ----
    for (int k0 = 0; k0 < 256; k0 += 64) {
#pragma unroll
      for (int r = 0; r < 4; r++) {
        int idx = r * 512 + tid;
        int row = idx >> 3, ch = idx & 7, gch = ch ^ (row & 7);
        *(fp16x8*)&sB[row * 64 + ch * 8] =
            *(const fp16x8*)&W2e[(size_t)row * 256 + k0 + gch * 8];
      }
      __syncthreads();
#pragma unroll
      for (int kk = 0; kk < 2; kk++) {
        fp16x8 a[4], bf[4];
        int kcg = kk * 4 + (lane >> 4);
#pragma unroll
        for (int i = 0; i < 4; i++) {
          int ar = wr * 64 + i * 16 + (lane & 15);
          a[i] = *(const fp16x8*)&sHE[ar * 264 + k0 + kk * 32 + (lane >> 4) * 8];
          int br = wc * 64 + i * 16 + (lane & 15);
          bf[i] = *(const fp16x8*)&sB[br * 64 + (kcg ^ (br & 7)) * 8];
        }
#pragma unroll
        for (int i = 0; i < 4; i++)
#pragma unroll
          for (int j = 0; j < 4; j++)
            acc[i][j] = __builtin_amdgcn_mfma_f32_16x16x32_f16(a[i], bf[j], acc[i][j], 0, 0, 0);
      }
      __syncthreads();
    }
#pragma unroll
    for (int j = 0; j < 4; j++) {
      int col = wc * 64 + j * 16 + (lane & 15);
      float bb = b2[e * 256 + col];
#pragma unroll
      for (int i = 0; i < 4; i++)
#pragma unroll
        for (int q = 0; q < 4; q++) {
          int row = wr * 64 + i * 16 + ((lane >> 4) << 2) + q;
          int tok = sTok[row];
          if (tok >= 0) {
            float v = (acc[i][j][q] + bb) * sW[row];
            size_t o = (size_t)tok * 256 + col;
            if (PASSB) y[o] += v; else y[o] = v;
          }
        }
    }
    __syncthreads();
  }
}

// ---------------- host-side orchestration ----------------
extern "C" void kernel_launch(void* const* d_in, const int* in_sizes, int n_in,
                              void* d_out, int out_size, void* d_ws, size_t ws_size,
                              hipStream_t stream) {
  const float* x   = (const float*)d_in[0];
  const float* bias= (const float*)d_in[1];
  const float* W1  = (const float*)d_in[2];
  const float* b1  = (const float*)d_in[3];
  const float* W2  = (const float*)d_in[4];
  const float* b2  = (const float*)d_in[5];
  const float* g1  = (const float*)d_in[6];
  const float* gb1 = (const float*)d_in[7];
  const float* g2  = (const float*)d_in[8];
  const float* gb2 = (const float*)d_in[9];
  const float* g3  = (const float*)d_in[10];
  const float* gb3 = (const float*)d_in[11];
  float* y    = (float*)d_out;                    // [B][256]
  float* pout = y + (size_t)BTOK * 256;           // [B][16]

  char* w = (char*)d_ws;
  auto alloc = [&](size_t bytes) -> char* {
    char* p = w;
    w += (bytes + 255) & ~(size_t)255;
    return p;
  };
  _Float16* xhi  = (_Float16*)alloc((size_t)BTOK * 256 * 2);
  _Float16* xlo  = (_Float16*)alloc((size_t)BTOK * 256 * 2);
  _Float16* h2hi = (_Float16*)alloc((size_t)BTOK * 256 * 2);
  _Float16* h2lo = (_Float16*)alloc((size_t)BTOK * 256 * 2);
  _Float16* g1Th = (_Float16*)alloc((size_t)256 * 1024 * 2);
  _Float16* g1Tl = (_Float16*)alloc((size_t)256 * 1024 * 2);
  _Float16* g2Th = (_Float16*)alloc((size_t)256 * 1024 * 2);
  _Float16* g2Tl = (_Float16*)alloc((size_t)256 * 1024 * 2);
  _Float16* W1T  = (_Float16*)alloc((size_t)16 * 65536 * 2);
  _Float16* W2T  = (_Float16*)alloc((size_t)16 * 65536 * 2);
  int*   idx0 = (int*)alloc((size_t)BTOK * 4);
  int*   idx1 = (int*)alloc((size_t)BTOK * 4);
  float* w0a  = (float*)alloc((size_t)BTOK * 4);
  float* w1a  = (float*)alloc((size_t)BTOK * 4);
  int*   ctrl = (int*)alloc(4096);
  int*   ambList = (int*)alloc((size_t)AMB_CAP * 4);
  int*   dExp0 = (int*)alloc(544 * 4);
  int*   dRow0 = (int*)alloc(544 * 4);
  int*   dExp1 = (int*)alloc(544 * 4);
  int*   dRow1 = (int*)alloc(544 * 4);
  const int LCAP = BTOK + 16 * 128;
  int*   tok0 = (int*)alloc((size_t)LCAP * 4);
  float* wl0  = (float*)alloc((size_t)LCAP * 4);
  int*   tok1 = (int*)alloc((size_t)LCAP * 4);
  float* wl1  = (float*)alloc((size_t)LCAP * 4);

  size_t used = (size_t)(w - (char*)d_ws);
  size_t remain = ws_size > used ? ws_size - used : 0;
  int CG = 4;
  while (CG < 64 && (size_t)(BTOK / CG) * 1024 * 4 + 1024 > remain) CG <<= 1;
  int MC = BTOK / CG;
  _Float16* h1hi = (_Float16*)alloc((size_t)MC * 1024 * 2);
  _Float16* h1lo = (_Float16*)alloc((size_t)MC * 1024 * 2);

  int* cnt0 = ctrl + 0;  int* cnt1 = ctrl + 16;
  int* off0 = ctrl + 32; int* off1 = ctrl + 48;
  int* cur0 = ctrl + 64; int* cur1 = ctrl + 80;
  int* nTiles = ctrl + 96;
  int* ambCnt = ctrl + 112;

  hipMemsetAsync(ctrl, 0, 4096, stream);
  hipMemsetAsync(tok0, 0xFF, (size_t)LCAP * 4, stream);
  hipMemsetAsync(tok1, 0xFF, (size_t)LCAP * 4, stream);

  dim3 tb(256);
  k_transpose_cvt<<<dim3(1024 / 32, 256 / 32, 1), tb, 0, stream>>>(g1, g1Th, g1Tl, 256, 1024);
  k_transpose_cvt<<<dim3(256 / 32, 1024 / 32, 1), tb, 0, stream>>>(g2, g2Th, g2Tl, 1024, 256);
  k_transpose_cvt<<<dim3(8, 8, 16), tb, 0, stream>>>(W1, W1T, nullptr, 256, 256);
  k_transpose_cvt<<<dim3(8, 8, 16), tb, 0, stream>>>(W2, W2T, nullptr, 256, 256);
  k_xcvt<<<(BTOK * 256 / 8 + 255) / 256, tb, 0, stream>>>(x, xhi, xlo, BTOK * 256 / 8);

  for (int c = 0; c < CG; c++) {
    const _Float16* xh = xhi + (size_t)c * MC * 256;
    const _Float16* xl = xlo + (size_t)c * MC * 256;
    k_gemm_split<<<dim3(1024 / 128, MC / 128), tb, 0, stream>>>(
        xh, xl, g1Th, g1Tl, gb1, h1hi, h1lo, MC, 1024, 256);
    k_gemm_split<<<dim3(256 / 128, MC / 128), tb, 0, stream>>>(
        h1hi, h1lo, g2Th, g2Tl, gb2,
        h2hi + (size_t)c * MC * 256, h2lo + (size_t)c * MC * 256, MC, 256, 1024);
  }

  k_gate3<<<BTOK / 16, tb, 0, stream>>>(h2hi, h2lo, g3, gb3, pout, idx0, idx1,
                                        w0a, w1a, ambCnt, ambList);
  k_refine<<<64, tb, 0, stream>>>(x, g1, gb1, g2, gb2, g3, gb3, ambCnt, ambList,
                                  pout, idx0, idx1, w0a, w1a);
  k_hist<<<BTOK / 256, tb, 0, stream>>>(idx0, idx1, cnt0, cnt1);
  k_offsets<<<1, 64, 0, stream>>>(cnt0, cnt1, off0, off1, cur0, cur1,
                                  dExp0, dRow0, dExp1, dRow1, nTiles);
  k_scatter<<<BTOK / 256, tb, 0, stream>>>(idx0, idx1, w0a, w1a, off0, off1,
                                           cur0, cur1, tok0, wl0, tok1, wl1);
  k_expert<0><<<528, 512, 0, stream>>>(xhi, bias, W1T, b1, W2T, b2,
                                       dExp0, dRow0, nTiles + 0, tok0, wl0, y);
  k_expert<1><<<528, 512, 0, stream>>>(xhi, bias, W1T, b1, W2T, b2,
                                       dExp1, dRow1, nTiles + 1, tok1, wl1, y);
}

// Round 2
// 807.506 us; speedup vs baseline: 1.2612x; 1.2612x over previous
//
#include <hip/hip_runtime.h>
#include <cstdint>
#include <cstddef>

// ---------------- problem constants ----------------
#define BTOK 65536
#define DDIM 256
#define NEXP 16
#define HDIM 256
#define ODIM 256
#define TAU2 1.2e-2f
#define TAU3 1.2e-4
#define AMB2_CAP 12288
#define AMB3_CAP 1024

typedef _Float16 fp16x8 __attribute__((ext_vector_type(8)));
typedef float    f32x4_t __attribute__((ext_vector_type(4)));

__device__ __forceinline__ void async_ld16(const void* g, void* l) {
  __builtin_amdgcn_global_load_lds(
      (const __attribute__((address_space(1))) unsigned int*)g,
      (__attribute__((address_space(3))) unsigned int*)l, 16, 0, 0);
}

// ---------------- weight transpose + f32->f16 hi/lo ----------------
__global__ __launch_bounds__(256) void k_transpose_cvt(
    const float* __restrict__ src, _Float16* __restrict__ dhi,
    _Float16* __restrict__ dlo, int R, int C) {
  __shared__ float s[32][33];
  int bz = blockIdx.z;
  size_t stride = (size_t)R * C;
  src += (size_t)bz * stride;
  dhi += (size_t)bz * stride;
  if (dlo) dlo += (size_t)bz * stride;
  int c0 = blockIdx.x * 32, r0 = blockIdx.y * 32;
  int tx = threadIdx.x & 31, ty = threadIdx.x >> 5;
  for (int k = 0; k < 32; k += 8)
    s[ty + k][tx] = src[(size_t)(r0 + ty + k) * C + c0 + tx];
  __syncthreads();
  for (int k = 0; k < 32; k += 8) {
    float v = s[tx][ty + k];
    _Float16 h = (_Float16)v;
    size_t o = (size_t)(c0 + ty + k) * R + r0 + tx;
    dhi[o] = h;
    if (dlo) dlo[o] = (_Float16)(v - (float)h);
  }
}

// ---------------- x fp32 -> f16 hi only ----------------
__global__ __launch_bounds__(256) void k_xcvt_hi(const float* __restrict__ x,
                                                 _Float16* __restrict__ xhi, int n8) {
  int i = blockIdx.x * 256 + threadIdx.x;
  if (i >= n8) return;
  const float4* p = (const float4*)x;
  float4 a = p[(size_t)i * 2], b = p[(size_t)i * 2 + 1];
  float v[8] = {a.x, a.y, a.z, a.w, b.x, b.y, b.z, b.w};
  fp16x8 hv;
#pragma unroll
  for (int j = 0; j < 8; j++) hv[j] = (_Float16)v[j];
  *(fp16x8*)(xhi + (size_t)i * 8) = hv;
}

// ---------------- fast single-f16 GEMM: C = relu(A @ B^T + bias) f16 -------
__global__ __launch_bounds__(256) void k_gemm_f16(
    const _Float16* __restrict__ A, const _Float16* __restrict__ B,
    const float* __restrict__ bias, _Float16* __restrict__ C,
    int M, int N, int K) {
  __shared__ _Float16 sA[128 * 32], sB[128 * 32];
  const int tid = threadIdx.x;
  const int lane = tid & 63;
  const int wave = tid >> 6;
  const int wr = wave >> 1, wc = wave & 1;
  const int m0 = blockIdx.y * 128, n0 = blockIdx.x * 128;
  f32x4_t zero4 = {0.f, 0.f, 0.f, 0.f};
  f32x4_t acc[4][4];
#pragma unroll
  for (int i = 0; i < 4; i++)
#pragma unroll
    for (int j = 0; j < 4; j++) acc[i][j] = zero4;

  for (int k0 = 0; k0 < K; k0 += 32) {
#pragma unroll
    for (int r = 0; r < 2; r++) {
      int idx = r * 256 + tid;
      int row = idx >> 2, ch = idx & 3;
      int gch = ch ^ (row & 3);
      async_ld16(A + (size_t)(m0 + row) * K + k0 + gch * 8, &sA[idx * 8]);
      async_ld16(B + (size_t)(n0 + row) * K + k0 + gch * 8, &sB[idx * 8]);
    }
    __syncthreads();
    fp16x8 a[4], b[4];
    int kc = lane >> 4;
#pragma unroll
    for (int i = 0; i < 4; i++) {
      int ar = wr * 64 + i * 16 + (lane & 15);
      a[i] = *(const fp16x8*)&sA[ar * 32 + ((kc ^ (ar & 3)) << 3)];
      int br = wc * 64 + i * 16 + (lane & 15);
      b[i] = *(const fp16x8*)&sB[br * 32 + ((kc ^ (br & 3)) << 3)];
    }
#pragma unroll
    for (int i = 0; i < 4; i++)
#pragma unroll
      for (int j = 0; j < 4; j++)
        acc[i][j] = __builtin_amdgcn_mfma_f32_16x16x32_f16(a[i], b[j], acc[i][j], 0, 0, 0);
    __syncthreads();
  }
#pragma unroll
  for (int j = 0; j < 4; j++) {
    int col = n0 + wc * 64 + j * 16 + (lane & 15);
    float bc = bias[col];
#pragma unroll
    for (int i = 0; i < 4; i++)
#pragma unroll
      for (int q = 0; q < 4; q++) {
        int row = m0 + wr * 64 + i * 16 + ((lane >> 4) << 2) + q;
        float v = acc[i][j][q] + bc;
        v = v > 0.f ? v : 0.f;
        C[(size_t)row * N + col] = (_Float16)v;
      }
  }
}

// ---------------- split-f16 GEMM (tier-2): relu(A@B^T+bias), hi/lo out -----
__global__ __launch_bounds__(256) void k_gemm_split(
    const _Float16* __restrict__ Ahi, const _Float16* __restrict__ Alo,
    const _Float16* __restrict__ Bhi, const _Float16* __restrict__ Blo,
    const float* __restrict__ bias,
    _Float16* __restrict__ Chi, _Float16* __restrict__ Clo,
    int M, int N, int K, const int* __restrict__ nAct) {
  int nA = *nAct;
  if (nA > M) nA = M;
  const int m0 = blockIdx.y * 128, n0 = blockIdx.x * 128;
  if (m0 >= nA) return;
  __shared__ _Float16 sAh[128 * 32], sAl[128 * 32], sBh[128 * 32], sBl[128 * 32];
  const int tid = threadIdx.x;
  const int lane = tid & 63;
  const int wave = tid >> 6;
  const int wr = wave >> 1, wc = wave & 1;
  f32x4_t zero4 = {0.f, 0.f, 0.f, 0.f};
  f32x4_t acc[4][4];
#pragma unroll
  for (int i = 0; i < 4; i++)
#pragma unroll
    for (int j = 0; j < 4; j++) acc[i][j] = zero4;

  for (int k0 = 0; k0 < K; k0 += 32) {
#pragma unroll
    for (int r = 0; r < 2; r++) {
      int idx = r * 256 + tid;
      int row = idx >> 2, ch = idx & 3;
      int gch = ch ^ (row & 3);
      size_t ga = (size_t)(m0 + row) * K + k0 + gch * 8;
      size_t gb = (size_t)(n0 + row) * K + k0 + gch * 8;
      async_ld16(Ahi + ga, &sAh[idx * 8]);
      async_ld16(Alo + ga, &sAl[idx * 8]);
      async_ld16(Bhi + gb, &sBh[idx * 8]);
      async_ld16(Blo + gb, &sBl[idx * 8]);
    }
    __syncthreads();
    fp16x8 ah[4], al[4], bh[4], bl[4];
    int kc = lane >> 4;
#pragma unroll
    for (int i = 0; i < 4; i++) {
      int ar = wr * 64 + i * 16 + (lane & 15);
      int offa = ar * 32 + ((kc ^ (ar & 3)) << 3);
      ah[i] = *(const fp16x8*)&sAh[offa];
      al[i] = *(const fp16x8*)&sAl[offa];
      int br = wc * 64 + i * 16 + (lane & 15);
      int offb = br * 32 + ((kc ^ (br & 3)) << 3);
      bh[i] = *(const fp16x8*)&sBh[offb];
      bl[i] = *(const fp16x8*)&sBl[offb];
    }
#pragma unroll
    for (int i = 0; i < 4; i++)
#pragma unroll
      for (int j = 0; j < 4; j++) {
        acc[i][j] = __builtin_amdgcn_mfma_f32_16x16x32_f16(ah[i], bh[j], acc[i][j], 0, 0, 0);
        acc[i][j] = __builtin_amdgcn_mfma_f32_16x16x32_f16(ah[i], bl[j], acc[i][j], 0, 0, 0);
        acc[i][j] = __builtin_amdgcn_mfma_f32_16x16x32_f16(al[i], bh[j], acc[i][j], 0, 0, 0);
      }
    __syncthreads();
  }
#pragma unroll
  for (int j = 0; j < 4; j++) {
    int col = n0 + wc * 64 + j * 16 + (lane & 15);
    float bc = bias[col];
#pragma unroll
    for (int i = 0; i < 4; i++)
#pragma unroll
      for (int q = 0; q < 4; q++) {
        int row = m0 + wr * 64 + i * 16 + ((lane >> 4) << 2) + q;
        float v = acc[i][j][q] + bc;
        v = v > 0.f ? v : 0.f;
        _Float16 h = (_Float16)v;
        size_t o = (size_t)row * N + col;
        Chi[o] = h;
        Clo[o] = (_Float16)(v - (float)h);
      }
  }
}

// ---------------- gate layer 3 FAST: fp32 logits + top2 + flag tier-2 ------
__global__ __launch_bounds__(256) void k_gate3_fast(
    const _Float16* __restrict__ h2h, const float* __restrict__ g3,
    const float* __restrict__ gb3,
    float* __restrict__ pout, int* __restrict__ idx0, int* __restrict__ idx1,
    float* __restrict__ w0, float* __restrict__ w1,
    int* __restrict__ amb2Cnt, int* __restrict__ amb2List) {
  __shared__ _Float16 shh[16 * 256];
  __shared__ float sg3[16][260];
  __shared__ float sgb[16];
  __shared__ float slog[16][17];
  __shared__ int sidx[16][2];
  __shared__ float swv[16][2];
  int tid = threadIdx.x;
  int tokBase = blockIdx.x * 16;
  {
    int t = tid >> 4, c = (tid & 15) * 16;
    size_t g = (size_t)(tokBase + t) * 256 + c;
    *(fp16x8*)&shh[t * 256 + c] = *(const fp16x8*)&h2h[g];
    *(fp16x8*)&shh[t * 256 + c + 8] = *(const fp16x8*)&h2h[g + 8];
  }
#pragma unroll
  for (int r = 0; r < 16; r++) {
    int j = r * 256 + tid;
    sg3[j & 15][j >> 4] = g3[j];
  }
  if (tid < 16) sgb[tid] = gb3[tid];
  __syncthreads();
  int t = tid >> 4, e = tid & 15;
  const _Float16* ph = &shh[t * 256];
  const float* pg = &sg3[e][0];
  float acc = 0.f;
  for (int k = 0; k < 256; k += 8) {
    fp16x8 hv = *(const fp16x8*)&ph[k];
    float4 ga = *(const float4*)&pg[k];
    float4 gb = *(const float4*)&pg[k + 4];
    acc = fmaf((float)hv[0], ga.x, acc);
    acc = fmaf((float)hv[1], ga.y, acc);
    acc = fmaf((float)hv[2], ga.z, acc);
    acc = fmaf((float)hv[3], ga.w, acc);
    acc = fmaf((float)hv[4], gb.x, acc);
    acc = fmaf((float)hv[5], gb.y, acc);
    acc = fmaf((float)hv[6], gb.z, acc);
    acc = fmaf((float)hv[7], gb.w, acc);
  }
  acc += sgb[e];
  slog[t][e] = acc;
  __syncthreads();
  if (e == 0) {
    float l[16];
#pragma unroll
    for (int i = 0; i < 16; i++) l[i] = slog[t][i];
    int i1 = 0;
    for (int i = 1; i < 16; i++) if (l[i] > l[i1]) i1 = i;
    int i2 = -1;
    for (int i = 0; i < 16; i++) { if (i == i1) continue; if (i2 < 0 || l[i] > l[i2]) i2 = i; }
    float l3 = -1e30f;
    for (int i = 0; i < 16; i++) { if (i == i1 || i == i2) continue; if (l[i] > l3) l3 = l[i]; }
    float lmax = l[i1];
    float S = 0.f;
    for (int i = 0; i < 16; i++) S += expf(l[i] - lmax);
    float p1 = 1.0f / S, p2 = expf(l[i2] - lmax) / S;
    float den = p1 + p2 + 1e-9f;
    sidx[t][0] = i1; sidx[t][1] = i2;
    swv[t][0] = p1 / den; swv[t][1] = p2 / den;
    if (l[i2] - l3 < TAU2) {
      int pos = atomicAdd(amb2Cnt, 1);
      if (pos < AMB2_CAP) amb2List[pos] = tokBase + t;
    }
  }
  __syncthreads();
  int i1 = sidx[t][0], i2 = sidx[t][1];
  float pv = (e == i1) ? swv[t][0] : ((e == i2) ? swv[t][1] : 0.f);
  pout[(size_t)(tokBase + t) * 16 + e] = pv;
  if (e == 0) {
    int tok = tokBase + t;
    idx0[tok] = i1; idx1[tok] = i2;
    w0[tok] = swv[t][0]; w1[tok] = swv[t][1];
  }
}

// ---------------- tier-2 gather: x -> xg hi/lo ----------------
__global__ __launch_bounds__(256) void k_gather2(
    const float* __restrict__ x, const int* __restrict__ cnt,
    const int* __restrict__ list,
    _Float16* __restrict__ xgh, _Float16* __restrict__ xgl) {
  int n = *cnt; if (n > AMB2_CAP) n = AMB2_CAP;
  int s = blockIdx.x * 8 + (threadIdx.x >> 5);
  if (s >= n) return;
  int tok = list[s];
  int c = (threadIdx.x & 31) * 8;
  const float4* p = (const float4*)&x[(size_t)tok * 256 + c];
  float4 a = p[0], b = p[1];
  float v[8] = {a.x, a.y, a.z, a.w, b.x, b.y, b.z, b.w};
  fp16x8 hv, lv;
#pragma unroll
  for (int j = 0; j < 8; j++) {
    _Float16 h = (_Float16)v[j];
    hv[j] = h;
    lv[j] = (_Float16)(v[j] - (float)h);
  }
  *(fp16x8*)&xgh[(size_t)s * 256 + c] = hv;
  *(fp16x8*)&xgl[(size_t)s * 256 + c] = lv;
}

// ---------------- tier-2 gate3 precise: fp64 logits, overwrite, flag t3 ----
__global__ __launch_bounds__(256) void k_gate3_precise(
    const _Float16* __restrict__ h2ghi, const _Float16* __restrict__ h2glo,
    const float* __restrict__ g3, const float* __restrict__ gb3,
    const int* __restrict__ amb2Cnt, const int* __restrict__ amb2List,
    float* __restrict__ pout, int* __restrict__ idx0, int* __restrict__ idx1,
    float* __restrict__ w0, float* __restrict__ w1,
    int* __restrict__ amb3Cnt, int* __restrict__ amb3List) {
  __shared__ _Float16 shh[16 * 256], shl[16 * 256];
  __shared__ float sg3[16][260];
  __shared__ float sgb[16];
  __shared__ double slog[16][17];
  __shared__ int sidx[16][2];
  __shared__ float swv[16][2];
  int tid = threadIdx.x;
  int slotBase = blockIdx.x * 16;
  int n2 = *amb2Cnt; if (n2 > AMB2_CAP) n2 = AMB2_CAP;
  {
    int t = tid >> 4, c = (tid & 15) * 16;
    size_t g = (size_t)(slotBase + t) * 256 + c;
    *(fp16x8*)&shh[t * 256 + c] = *(const fp16x8*)&h2ghi[g];
    *(fp16x8*)&shh[t * 256 + c + 8] = *(const fp16x8*)&h2ghi[g + 8];
    *(fp16x8*)&shl[t * 256 + c] = *(const fp16x8*)&h2glo[g];
    *(fp16x8*)&shl[t * 256 + c + 8] = *(const fp16x8*)&h2glo[g + 8];
  }
#pragma unroll
  for (int r = 0; r < 16; r++) {
    int j = r * 256 + tid;
    sg3[j & 15][j >> 4] = g3[j];
  }
  if (tid < 16) sgb[tid] = gb3[tid];
  __syncthreads();
  int t = tid >> 4, e = tid & 15;
  int slot = slotBase + t;
  const _Float16* ph = &shh[t * 256];
  const _Float16* pl = &shl[t * 256];
  const float* pg = &sg3[e][0];
  double acc = 0.0;
  for (int k = 0; k < 256; k += 4) {
#pragma unroll
    for (int j = 0; j < 4; j++) {
      double a = (double)(float)ph[k + j] + (double)(float)pl[k + j];
      acc = fma(a, (double)pg[k + j], acc);
    }
  }
  acc += (double)sgb[e];
  slog[t][e] = acc;
  __syncthreads();
  if (e == 0 && slot < n2) {
    double l[16];
#pragma unroll
    for (int i = 0; i < 16; i++) l[i] = slog[t][i];
    int i1 = 0;
    for (int i = 1; i < 16; i++) if (l[i] > l[i1]) i1 = i;
    int i2 = -1;
    for (int i = 0; i < 16; i++) { if (i == i1) continue; if (i2 < 0 || l[i] > l[i2]) i2 = i; }
    double l3 = -1e300;
    for (int i = 0; i < 16; i++) { if (i == i1 || i == i2) continue; if (l[i] > l3) l3 = l[i]; }
    double lmax = l[i1];
    double S = 0.0;
    for (int i = 0; i < 16; i++) S += exp(l[i] - lmax);
    double p1 = 1.0 / S, p2 = exp(l[i2] - lmax) / S;
    double den = p1 + p2 + 1e-9;
    sidx[t][0] = i1; sidx[t][1] = i2;
    swv[t][0] = (float)(p1 / den); swv[t][1] = (float)(p2 / den);
    if (l[i2] - l3 < TAU3) {
      int pos = atomicAdd(amb3Cnt, 1);
      if (pos < AMB3_CAP) amb3List[pos] = amb2List[slot];
    }
  }
  __syncthreads();
  if (slot < n2) {
    int tok = amb2List[slot];
    int i1 = sidx[t][0], i2 = sidx[t][1];
    float pv = (e == i1) ? swv[t][0] : ((e == i2) ? swv[t][1] : 0.f);
    pout[(size_t)tok * 16 + e] = pv;
    if (e == 0) {
      idx0[tok] = i1; idx1[tok] = i2;
      w0[tok] = swv[t][0]; w1[tok] = swv[t][1];
    }
  }
}

// ---------------- tier-3: parallel fp64 exact recompute ----------------
__global__ __launch_bounds__(256) void k_refine_par(
    const float* __restrict__ x,
    const float* __restrict__ g1, const float* __restrict__ gb1,
    const float* __restrict__ g2, const float* __restrict__ gb2,
    const float* __restrict__ g3, const float* __restrict__ gb3,
    const int* __restrict__ cnt, const int* __restrict__ list,
    float* __restrict__ pout, int* __restrict__ idx0, int* __restrict__ idx1,
    float* __restrict__ w0, float* __restrict__ w1) {
  __shared__ float sx[256];
  __shared__ double sh1[1024];
  __shared__ double sred[4][256];
  __shared__ double sh2[256];
  __shared__ double sl16[16][17];
  __shared__ int sidx[2];
  __shared__ float swv[2];
  int tid = threadIdx.x;
  int n = *cnt; if (n > AMB3_CAP) n = AMB3_CAP;
  for (int ii = blockIdx.x; ii < n; ii += gridDim.x) {
    int tok = list[ii];
    sx[tid] = x[(size_t)tok * 256 + tid];
    __syncthreads();
    // L1: thread -> outputs 4t..4t+3, float4 coalesced weight loads
    {
      double a0 = 0, a1 = 0, a2 = 0, a3 = 0;
      const float* gp = g1 + tid * 4;
#pragma unroll 4
      for (int k = 0; k < 256; k++) {
        float4 gv = *(const float4*)(gp + (size_t)k * 1024);
        double xv = (double)sx[k];
        a0 = fma(xv, (double)gv.x, a0);
        a1 = fma(xv, (double)gv.y, a1);
        a2 = fma(xv, (double)gv.z, a2);
        a3 = fma(xv, (double)gv.w, a3);
      }
      double b0 = a0 + (double)gb1[tid * 4 + 0];
      double b1v = a1 + (double)gb1[tid * 4 + 1];
      double b2v = a2 + (double)gb1[tid * 4 + 2];
      double b3v = a3 + (double)gb1[tid * 4 + 3];
      sh1[tid * 4 + 0] = b0 > 0 ? b0 : 0.0;
      sh1[tid * 4 + 1] = b1v > 0 ? b1v : 0.0;
      sh1[tid * 4 + 2] = b2v > 0 ? b2v : 0.0;
      sh1[tid * 4 + 3] = b3v > 0 ? b3v : 0.0;
    }
    __syncthreads();
    // L2: split-K 4 x (outputs 4og..4og+3)
    {
      int p = tid >> 6, og = tid & 63;
      double a0 = 0, a1 = 0, a2 = 0, a3 = 0;
      const float* gp = g2 + og * 4 + (size_t)(p * 256) * 256;
      const double* hp = &sh1[p * 256];
#pragma unroll 4
      for (int k = 0; k < 256; k++) {
        float4 gv = *(const float4*)(gp + (size_t)k * 256);
        double hv = hp[k];
        a0 = fma(hv, (double)gv.x, a0);
        a1 = fma(hv, (double)gv.y, a1);
        a2 = fma(hv, (double)gv.z, a2);
        a3 = fma(hv, (double)gv.w, a3);
      }
      sred[p][og * 4 + 0] = a0;
      sred[p][og * 4 + 1] = a1;
      sred[p][og * 4 + 2] = a2;
      sred[p][og * 4 + 3] = a3;
    }
    __syncthreads();
    {
      double s = sred[0][tid] + sred[1][tid] + sred[2][tid] + sred[3][tid] + (double)gb2[tid];
      sh2[tid] = s > 0 ? s : 0.0;
    }
    __syncthreads();
    // L3: 16 outputs x 16 k-parts
    {
      int o = tid & 15, p = tid >> 4;
      double a = 0;
      const float* gp = g3 + o;
#pragma unroll
      for (int k = p * 16; k < p * 16 + 16; k++)
        a = fma(sh2[k], (double)gp[(size_t)k * 16], a);
      sl16[p][o] = a;
    }
    __syncthreads();
    if (tid == 0) {
      double l[16];
      for (int o = 0; o < 16; o++) {
        double a = (double)gb3[o];
        for (int p = 0; p < 16; p++) a += sl16[p][o];
        l[o] = a;
      }
      int i1 = 0;
      for (int i = 1; i < 16; i++) if (l[i] > l[i1]) i1 = i;
      int i2 = -1;
      for (int i = 0; i < 16; i++) { if (i == i1) continue; if (i2 < 0 || l[i] > l[i2]) i2 = i; }
      double lmax = l[i1];
      double S = 0.0;
      for (int i = 0; i < 16; i++) S += exp(l[i] - lmax);
      double p1 = 1.0 / S, p2 = exp(l[i2] - lmax) / S;
      double den = p1 + p2 + 1e-9;
      float fw0 = (float)(p1 / den), fw1 = (float)(p2 / den);
      sidx[0] = i1; sidx[1] = i2;
      swv[0] = fw0; swv[1] = fw1;
      idx0[tok] = i1; idx1[tok] = i2;
      w0[tok] = fw0; w1[tok] = fw1;
    }
    __syncthreads();
    if (tid < 16) {
      float pv = (tid == sidx[0]) ? swv[0] : ((tid == sidx[1]) ? swv[1] : 0.f);
      pout[(size_t)tok * 16 + tid] = pv;
    }
    __syncthreads();
  }
}

// ---------------- bucket-by-expert: histogram / offsets / scatter ----------
__global__ __launch_bounds__(256) void k_hist(const int* __restrict__ idx0,
                                              const int* __restrict__ idx1,
                                              int* __restrict__ cnt0, int* __restrict__ cnt1) {
  __shared__ int c0[16], c1[16];
  int tid = threadIdx.x;
  if (tid < 16) { c0[tid] = 0; c1[tid] = 0; }
  __syncthreads();
  int b = blockIdx.x * 256 + tid;
  atomicAdd(&c0[idx0[b]], 1);
  atomicAdd(&c1[idx1[b]], 1);
  __syncthreads();
  if (tid < 16) { atomicAdd(&cnt0[tid], c0[tid]); atomicAdd(&cnt1[tid], c1[tid]); }
}

__global__ void k_offsets(const int* __restrict__ cnt0, const int* __restrict__ cnt1,
                          int* off0, int* off1, int* cur0, int* cur1,
                          int* dExp0, int* dRow0, int* dExp1, int* dRow1, int* nTiles) {
  if (threadIdx.x == 0) {
    int tot = 0, nt = 0;
    for (int e = 0; e < 16; e++) {
      off0[e] = tot; cur0[e] = 0;
      int tiles = (cnt0[e] + 127) >> 7;
      for (int ti = 0; ti < tiles; ti++) { dExp0[nt] = e; dRow0[nt] = tot + ti * 128; nt++; }
      tot += tiles * 128;
    }
    nTiles[0] = nt;
    tot = 0; nt = 0;
    for (int e = 0; e < 16; e++) {
      off1[e] = tot; cur1[e] = 0;
      int tiles = (cnt1[e] + 127) >> 7;
      for (int ti = 0; ti < tiles; ti++) { dExp1[nt] = e; dRow1[nt] = tot + ti * 128; nt++; }
      tot += tiles * 128;
    }
    nTiles[1] = nt;
  }
}

__global__ __launch_bounds__(256) void k_scatter(
    const int* __restrict__ idx0, const int* __restrict__ idx1,
    const float* __restrict__ w0, const float* __restrict__ w1,
    const int* __restrict__ off0, const int* __restrict__ off1,
    int* cur0, int* cur1,
    int* __restrict__ tok0, float* __restrict__ wl0,
    int* __restrict__ tok1, float* __restrict__ wl1) {
  __shared__ int c0[16], c1[16], b0[16], b1[16];
  int tid = threadIdx.x;
  if (tid < 16) { c0[tid] = 0; c1[tid] = 0; }
  __syncthreads();
  int b = blockIdx.x * 256 + tid;
  int e0 = idx0[b], e1 = idx1[b];
  int r0 = atomicAdd(&c0[e0], 1);
  int r1 = atomicAdd(&c1[e1], 1);
  __syncthreads();
  if (tid < 16) { b0[tid] = atomicAdd(&cur0[tid], c0[tid]); b1[tid] = atomicAdd(&cur1[tid], c1[tid]); }
  __syncthreads();
  int p0 = off0[e0] + b0[e0] + r0;
  tok0[p0] = b; wl0[p0] = w0[b];
  int p1 = off1[e1] + b1[e1] + r1;
  tok1[p1] = b; wl1[p1] = w1[b];
}

// ---------------- fused 2-layer expert MLP, grouped by expert --------------
template <int PASSB>
__global__ __launch_bounds__(512) void k_expert(
    const _Float16* __restrict__ xhi, const float* __restrict__ bias,
    const _Float16* __restrict__ W1T, const float* __restrict__ b1,
    const _Float16* __restrict__ W2T, const float* __restrict__ b2,
    const int* __restrict__ dExp, const int* __restrict__ dRow,
    const int* __restrict__ nT,
    const int* __restrict__ tokL, const float* __restrict__ wL,
    float* __restrict__ y) {
  __shared__ _Float16 sA[128 * 64];
  __shared__ _Float16 sB[256 * 64];
  __shared__ _Float16 sHE[128 * 264];
  __shared__ int sTok[128];
  __shared__ float sW[128];
  int tid = threadIdx.x, lane = tid & 63, wave = tid >> 6;
  int wr = wave >> 2, wc = wave & 3;
  f32x4_t zero4 = {0.f, 0.f, 0.f, 0.f};
  int nt = *nT;
  for (int t = blockIdx.x; t < nt; t += gridDim.x) {
    int e = dExp[t], rowOff = dRow[t];
    if (tid < 128) { sTok[tid] = tokL[rowOff + tid]; sW[tid] = wL[rowOff + tid]; }
    __syncthreads();
    f32x4_t acc[4][4];
#pragma unroll
    for (int i = 0; i < 4; i++)
#pragma unroll
      for (int j = 0; j < 4; j++) acc[i][j] = zero4;
    const _Float16* W1e = W1T + (size_t)e * 65536;
    const _Float16* W2e = W2T + (size_t)e * 65536;
    const float* be = bias + e * 256;
    for (int k0 = 0; k0 < 256; k0 += 64) {
#pragma unroll
      for (int r = 0; r < 2; r++) {
        int idx = r * 512 + tid;
        int row = idx >> 3, ch = idx & 7, gch = ch ^ (row & 7);
        int tok = sTok[row];
        int tk = tok < 0 ? 0 : tok;
        fp16x8 v = *(const fp16x8*)&xhi[(size_t)tk * 256 + k0 + gch * 8];
        const float* bp = &be[k0 + gch * 8];
#pragma unroll
        for (int j = 0; j < 8; j++) v[j] = (_Float16)((float)v[j] + bp[j]);
        *(fp16x8*)&sA[row * 64 + ch * 8] = v;
      }
#pragma unroll
      for (int r = 0; r < 4; r++) {
        int idx = r * 512 + tid;
        int row = idx >> 3, ch = idx & 7, gch = ch ^ (row & 7);
        *(fp16x8*)&sB[row * 64 + ch * 8] =
            *(const fp16x8*)&W1e[(size_t)row * 256 + k0 + gch * 8];
      }
      __syncthreads();
#pragma unroll
      for (int kk = 0; kk < 2; kk++) {
        fp16x8 a[4], bf[4];
        int kcg = kk * 4 + (lane >> 4);
#pragma unroll
        for (int i = 0; i < 4; i++) {
          int ar = wr * 64 + i * 16 + (lane & 15);
          a[i] = *(const fp16x8*)&sA[ar * 64 + (kcg ^ (ar & 7)) * 8];
          int br = wc * 64 + i * 16 + (lane & 15);
          bf[i] = *(const fp16x8*)&sB[br * 64 + (kcg ^ (br & 7)) * 8];
        }
#pragma unroll
        for (int i = 0; i < 4; i++)
#pragma unroll
          for (int j = 0; j < 4; j++)
            acc[i][j] = __builtin_amdgcn_mfma_f32_16x16x32_f16(a[i], bf[j], acc[i][j], 0, 0, 0);
      }
      __syncthreads();
    }
#pragma unroll
    for (int j = 0; j < 4; j++) {
      int col = wc * 64 + j * 16 + (lane & 15);
      float bb = b1[e * 256 + col];
#pragma unroll
      for (int i = 0; i < 4; i++)
#pragma unroll
        for (int q = 0; q < 4; q++) {
          int row = wr * 64 + i * 16 + ((lane >> 4) << 2) + q;
          float v = acc[i][j][q] + bb;
          v = v > 0.f ? v : 0.f;
          sHE[row * 264 + col] = (_Float16)v;
        }
    }
#pragma unroll
    for (int i = 0; i < 4; i++)
#pragma unroll
      for (int j = 0; j < 4; j++) acc[i][j] = zero4;
    __syncthreads();
    for (int k0 = 0; k0 < 256; k0 += 64) {
#pragma unroll
      for (int r = 0; r < 4; r++) {
        int idx = r * 512 + tid;
        int row = idx >> 3, ch = idx & 7, gch = ch ^ (row & 7);
        *(fp16x8*)&sB[row * 64 + ch * 8] =
            *(const fp16x8*)&W2e[(size_t)row * 256 + k0 + gch * 8];
      }
      __syncthreads();
#pragma unroll
      for (int kk = 0; kk < 2; kk++) {
        fp16x8 a[4], bf[4];
        int kcg = kk * 4 + (lane >> 4);
#pragma unroll
        for (int i = 0; i < 4; i++) {
          int ar = wr * 64 + i * 16 + (lane & 15);
          a[i] = *(const fp16x8*)&sHE[ar * 264 + k0 + kk * 32 + (lane >> 4) * 8];
          int br = wc * 64 + i * 16 + (lane & 15);
          bf[i] = *(const fp16x8*)&sB[br * 64 + (kcg ^ (br & 7)) * 8];
        }
#pragma unroll
        for (int i = 0; i < 4; i++)
#pragma unroll
          for (int j = 0; j < 4; j++)
            acc[i][j] = __builtin_amdgcn_mfma_f32_16x16x32_f16(a[i], bf[j], acc[i][j], 0, 0, 0);
      }
      __syncthreads();
    }
#pragma unroll
    for (int j = 0; j < 4; j++) {
      int col = wc * 64 + j * 16 + (lane & 15);
      float bb = b2[e * 256 + col];
#pragma unroll
      for (int i = 0; i < 4; i++)
#pragma unroll
        for (int q = 0; q < 4; q++) {
          int row = wr * 64 + i * 16 + ((lane >> 4) << 2) + q;
          int tok = sTok[row];
          if (tok >= 0) {
            float v = (acc[i][j][q] + bb) * sW[row];
            size_t o = (size_t)tok * 256 + col;
            if (PASSB) y[o] += v; else y[o] = v;
          }
        }
    }
    __syncthreads();
  }
}

// ---------------- host-side orchestration ----------------
extern "C" void kernel_launch(void* const* d_in, const int* in_sizes, int n_in,
                              void* d_out, int out_size, void* d_ws, size_t ws_size,
                              hipStream_t stream) {
  const float* x   = (const float*)d_in[0];
  const float* bias= (const float*)d_in[1];
  const float* W1  = (const float*)d_in[2];
  const float* b1  = (const float*)d_in[3];
  const float* W2  = (const float*)d_in[4];
  const float* b2  = (const float*)d_in[5];
  const float* g1  = (const float*)d_in[6];
  const float* gb1 = (const float*)d_in[7];
  const float* g2  = (const float*)d_in[8];
  const float* gb2 = (const float*)d_in[9];
  const float* g3  = (const float*)d_in[10];
  const float* gb3 = (const float*)d_in[11];
  float* y    = (float*)d_out;
  float* pout = y + (size_t)BTOK * 256;

  char* w = (char*)d_ws;
  auto alloc = [&](size_t bytes) -> char* {
    char* p = w;
    w += (bytes + 255) & ~(size_t)255;
    return p;
  };
  _Float16* xhi  = (_Float16*)alloc((size_t)BTOK * 256 * 2);
  _Float16* h2h  = (_Float16*)alloc((size_t)BTOK * 256 * 2);
  _Float16* g1Th = (_Float16*)alloc((size_t)256 * 1024 * 2);
  _Float16* g1Tl = (_Float16*)alloc((size_t)256 * 1024 * 2);
  _Float16* g2Th = (_Float16*)alloc((size_t)256 * 1024 * 2);
  _Float16* g2Tl = (_Float16*)alloc((size_t)256 * 1024 * 2);
  _Float16* W1T  = (_Float16*)alloc((size_t)16 * 65536 * 2);
  _Float16* W2T  = (_Float16*)alloc((size_t)16 * 65536 * 2);
  int*   idx0 = (int*)alloc((size_t)BTOK * 4);
  int*   idx1 = (int*)alloc((size_t)BTOK * 4);
  float* w0a  = (float*)alloc((size_t)BTOK * 4);
  float* w1a  = (float*)alloc((size_t)BTOK * 4);
  int*   ctrl = (int*)alloc(4096);
  int*   amb2List = (int*)alloc((size_t)AMB2_CAP * 4);
  int*   amb3List = (int*)alloc((size_t)AMB3_CAP * 4);
  int*   dExp0 = (int*)alloc(544 * 4);
  int*   dRow0 = (int*)alloc(544 * 4);
  int*   dExp1 = (int*)alloc(544 * 4);
  int*   dRow1 = (int*)alloc(544 * 4);
  const int LCAP = BTOK + 16 * 128;
  int*   tok0 = (int*)alloc((size_t)LCAP * 4);
  float* wl0  = (float*)alloc((size_t)LCAP * 4);
  int*   tok1 = (int*)alloc((size_t)LCAP * 4);
  float* wl1  = (float*)alloc((size_t)LCAP * 4);
  // tier-2 buffers
  _Float16* xgh  = (_Float16*)alloc((size_t)AMB2_CAP * 256 * 2);
  _Float16* xgl  = (_Float16*)alloc((size_t)AMB2_CAP * 256 * 2);
  _Float16* h1gh = (_Float16*)alloc((size_t)AMB2_CAP * 1024 * 2);
  _Float16* h1gl = (_Float16*)alloc((size_t)AMB2_CAP * 1024 * 2);
  _Float16* h2gh = (_Float16*)alloc((size_t)AMB2_CAP * 256 * 2);
  _Float16* h2gl = (_Float16*)alloc((size_t)AMB2_CAP * 256 * 2);

  size_t used = (size_t)(w - (char*)d_ws);
  size_t remain = ws_size > used ? ws_size - used : 0;
  int CG = 1;
  while (CG < 64 && (size_t)(BTOK / CG) * 1024 * 2 + 1024 > remain) CG <<= 1;
  int MC = BTOK / CG;
  _Float16* h1h = (_Float16*)alloc((size_t)MC * 1024 * 2);

  int* cnt0 = ctrl + 0;  int* cnt1 = ctrl + 16;
  int* off0 = ctrl + 32; int* off1 = ctrl + 48;
  int* cur0 = ctrl + 64; int* cur1 = ctrl + 80;
  int* nTiles = ctrl + 96;
  int* amb2Cnt = ctrl + 112;
  int* amb3Cnt = ctrl + 116;

  hipMemsetAsync(ctrl, 0, 4096, stream);
  hipMemsetAsync(tok0, 0xFF, (size_t)LCAP * 4, stream);
  hipMemsetAsync(tok1, 0xFF, (size_t)LCAP * 4, stream);

  dim3 tb(256);
  k_transpose_cvt<<<dim3(32, 8, 1), tb, 0, stream>>>(g1, g1Th, g1Tl, 256, 1024);
  k_transpose_cvt<<<dim3(8, 32, 1), tb, 0, stream>>>(g2, g2Th, g2Tl, 1024, 256);
  k_transpose_cvt<<<dim3(8, 8, 16), tb, 0, stream>>>(W1, W1T, nullptr, 256, 256);
  k_transpose_cvt<<<dim3(8, 8, 16), tb, 0, stream>>>(W2, W2T, nullptr, 256, 256);
  k_xcvt_hi<<<(BTOK * 256 / 8 + 255) / 256, tb, 0, stream>>>(x, xhi, BTOK * 256 / 8);

  // ---- fast gate (single f16) ----
  for (int c = 0; c < CG; c++) {
    const _Float16* xh = xhi + (size_t)c * MC * 256;
    k_gemm_f16<<<dim3(8, MC / 128), tb, 0, stream>>>(xh, g1Th, gb1, h1h, MC, 1024, 256);
    k_gemm_f16<<<dim3(2, MC / 128), tb, 0, stream>>>(h1h, g2Th, gb2,
                                                     h2h + (size_t)c * MC * 256, MC, 256, 1024);
  }
  k_gate3_fast<<<BTOK / 16, tb, 0, stream>>>(h2h, g3, gb3, pout, idx0, idx1,
                                             w0a, w1a, amb2Cnt, amb2List);

  // ---- tier-2: split-f16 precise gate on near-tie tokens ----
  k_gather2<<<AMB2_CAP / 8, tb, 0, stream>>>(x, amb2Cnt, amb2List, xgh, xgl);
  k_gemm_split<<<dim3(8, AMB2_CAP / 128), tb, 0, stream>>>(
      xgh, xgl, g1Th, g1Tl, gb1, h1gh, h1gl, AMB2_CAP, 1024, 256, amb2Cnt);
  k_gemm_split<<<dim3(2, AMB2_CAP / 128), tb, 0, stream>>>(
      h1gh, h1gl, g2Th, g2Tl, gb2, h2gh, h2gl, AMB2_CAP, 256, 1024, amb2Cnt);
  k_gate3_precise<<<AMB2_CAP / 16, tb, 0, stream>>>(
      h2gh, h2gl, g3, gb3, amb2Cnt, amb2List, pout, idx0, idx1, w0a, w1a,
      amb3Cnt, amb3List);

  // ---- tier-3: parallel fp64 ----
  k_refine_par<<<512, tb, 0, stream>>>(x, g1, gb1, g2, gb2, g3, gb3,
                                       amb3Cnt, amb3List, pout, idx0, idx1, w0a, w1a);

  // ---- expert buckets + fused expert MLP ----
  k_hist<<<BTOK / 256, tb, 0, stream>>>(idx0, idx1, cnt0, cnt1);
  k_offsets<<<1, 64, 0, stream>>>(cnt0, cnt1, off0, off1, cur0, cur1,
                                  dExp0, dRow0, dExp1, dRow1, nTiles);
  k_scatter<<<BTOK / 256, tb, 0, stream>>>(idx0, idx1, w0a, w1a, off0, off1,
                                           cur0, cur1, tok0, wl0, tok1, wl1);
  k_expert<0><<<528, 512, 0, stream>>>(xhi, bias, W1T, b1, W2T, b2,
                                       dExp0, dRow0, nTiles + 0, tok0, wl0, y);
  k_expert<1><<<528, 512, 0, stream>>>(xhi, bias, W1T, b1, W2T, b2,
                                       dExp1, dRow1, nTiles + 1, tok1, wl1, y);
}

// Round 3
// 686.002 us; speedup vs baseline: 1.4846x; 1.1771x over previous
//
#include <hip/hip_runtime.h>
#include <cstdint>
#include <cstddef>

// ---------------- problem constants ----------------
#define BTOK 65536
#define DDIM 256
#define NEXP 16
#define HDIM 256
#define ODIM 256
#define TAU2 1.2e-2f
#define TAU3 1.2e-4
#define AMB2_CAP 12288
#define AMB3_CAP 1024

typedef _Float16 fp16x8 __attribute__((ext_vector_type(8)));
typedef float    f32x4_t __attribute__((ext_vector_type(4)));

__device__ __forceinline__ void async_ld16(const void* g, void* l) {
  __builtin_amdgcn_global_load_lds(
      (const __attribute__((address_space(1))) unsigned int*)g,
      (__attribute__((address_space(3))) unsigned int*)l, 16, 0, 0);
}

// ---------------- weight transpose + f32->f16 hi/lo ----------------
__global__ __launch_bounds__(256) void k_transpose_cvt(
    const float* __restrict__ src, _Float16* __restrict__ dhi,
    _Float16* __restrict__ dlo, int R, int C) {
  __shared__ float s[32][33];
  int bz = blockIdx.z;
  size_t stride = (size_t)R * C;
  src += (size_t)bz * stride;
  dhi += (size_t)bz * stride;
  if (dlo) dlo += (size_t)bz * stride;
  int c0 = blockIdx.x * 32, r0 = blockIdx.y * 32;
  int tx = threadIdx.x & 31, ty = threadIdx.x >> 5;
  for (int k = 0; k < 32; k += 8)
    s[ty + k][tx] = src[(size_t)(r0 + ty + k) * C + c0 + tx];
  __syncthreads();
  for (int k = 0; k < 32; k += 8) {
    float v = s[tx][ty + k];
    _Float16 h = (_Float16)v;
    size_t o = (size_t)(c0 + ty + k) * R + r0 + tx;
    dhi[o] = h;
    if (dlo) dlo[o] = (_Float16)(v - (float)h);
  }
}

// ---------------- x fp32 -> f16 hi only ----------------
__global__ __launch_bounds__(256) void k_xcvt_hi(const float* __restrict__ x,
                                                 _Float16* __restrict__ xhi, int n8) {
  int i = blockIdx.x * 256 + threadIdx.x;
  if (i >= n8) return;
  const float4* p = (const float4*)x;
  float4 a = p[(size_t)i * 2], b = p[(size_t)i * 2 + 1];
  float v[8] = {a.x, a.y, a.z, a.w, b.x, b.y, b.z, b.w};
  fp16x8 hv;
#pragma unroll
  for (int j = 0; j < 8; j++) hv[j] = (_Float16)v[j];
  *(fp16x8*)(xhi + (size_t)i * 8) = hv;
}

// ---------------- fast single-f16 GEMM: C = relu(A @ B^T + bias) f16 -------
__global__ __launch_bounds__(256) void k_gemm_f16(
    const _Float16* __restrict__ A, const _Float16* __restrict__ B,
    const float* __restrict__ bias, _Float16* __restrict__ C,
    int M, int N, int K) {
  __shared__ _Float16 sA[128 * 32], sB[128 * 32];
  const int tid = threadIdx.x;
  const int lane = tid & 63;
  const int wave = tid >> 6;
  const int wr = wave >> 1, wc = wave & 1;
  const int m0 = blockIdx.y * 128, n0 = blockIdx.x * 128;
  f32x4_t zero4 = {0.f, 0.f, 0.f, 0.f};
  f32x4_t acc[4][4];
#pragma unroll
  for (int i = 0; i < 4; i++)
#pragma unroll
    for (int j = 0; j < 4; j++) acc[i][j] = zero4;

  for (int k0 = 0; k0 < K; k0 += 32) {
#pragma unroll
    for (int r = 0; r < 2; r++) {
      int idx = r * 256 + tid;
      int row = idx >> 2, ch = idx & 3;
      int gch = ch ^ (row & 3);
      async_ld16(A + (size_t)(m0 + row) * K + k0 + gch * 8, &sA[idx * 8]);
      async_ld16(B + (size_t)(n0 + row) * K + k0 + gch * 8, &sB[idx * 8]);
    }
    __syncthreads();
    fp16x8 a[4], b[4];
    int kc = lane >> 4;
#pragma unroll
    for (int i = 0; i < 4; i++) {
      int ar = wr * 64 + i * 16 + (lane & 15);
      a[i] = *(const fp16x8*)&sA[ar * 32 + ((kc ^ (ar & 3)) << 3)];
      int br = wc * 64 + i * 16 + (lane & 15);
      b[i] = *(const fp16x8*)&sB[br * 32 + ((kc ^ (br & 3)) << 3)];
    }
#pragma unroll
    for (int i = 0; i < 4; i++)
#pragma unroll
      for (int j = 0; j < 4; j++)
        acc[i][j] = __builtin_amdgcn_mfma_f32_16x16x32_f16(a[i], b[j], acc[i][j], 0, 0, 0);
    __syncthreads();
  }
#pragma unroll
  for (int j = 0; j < 4; j++) {
    int col = n0 + wc * 64 + j * 16 + (lane & 15);
    float bc = bias[col];
#pragma unroll
    for (int i = 0; i < 4; i++)
#pragma unroll
      for (int q = 0; q < 4; q++) {
        int row = m0 + wr * 64 + i * 16 + ((lane >> 4) << 2) + q;
        float v = acc[i][j][q] + bc;
        v = v > 0.f ? v : 0.f;
        C[(size_t)row * N + col] = (_Float16)v;
      }
  }
}

// ---------------- split-f16 GEMM (tier-2): relu(A@B^T+bias), hi/lo out -----
__global__ __launch_bounds__(256) void k_gemm_split(
    const _Float16* __restrict__ Ahi, const _Float16* __restrict__ Alo,
    const _Float16* __restrict__ Bhi, const _Float16* __restrict__ Blo,
    const float* __restrict__ bias,
    _Float16* __restrict__ Chi, _Float16* __restrict__ Clo,
    int M, int N, int K, const int* __restrict__ nAct) {
  int nA = *nAct;
  if (nA > M) nA = M;
  const int m0 = blockIdx.y * 128, n0 = blockIdx.x * 128;
  if (m0 >= nA) return;
  __shared__ _Float16 sAh[128 * 32], sAl[128 * 32], sBh[128 * 32], sBl[128 * 32];
  const int tid = threadIdx.x;
  const int lane = tid & 63;
  const int wave = tid >> 6;
  const int wr = wave >> 1, wc = wave & 1;
  f32x4_t zero4 = {0.f, 0.f, 0.f, 0.f};
  f32x4_t acc[4][4];
#pragma unroll
  for (int i = 0; i < 4; i++)
#pragma unroll
    for (int j = 0; j < 4; j++) acc[i][j] = zero4;

  for (int k0 = 0; k0 < K; k0 += 32) {
#pragma unroll
    for (int r = 0; r < 2; r++) {
      int idx = r * 256 + tid;
      int row = idx >> 2, ch = idx & 3;
      int gch = ch ^ (row & 3);
      size_t ga = (size_t)(m0 + row) * K + k0 + gch * 8;
      size_t gb = (size_t)(n0 + row) * K + k0 + gch * 8;
      async_ld16(Ahi + ga, &sAh[idx * 8]);
      async_ld16(Alo + ga, &sAl[idx * 8]);
      async_ld16(Bhi + gb, &sBh[idx * 8]);
      async_ld16(Blo + gb, &sBl[idx * 8]);
    }
    __syncthreads();
    fp16x8 ah[4], al[4], bh[4], bl[4];
    int kc = lane >> 4;
#pragma unroll
    for (int i = 0; i < 4; i++) {
      int ar = wr * 64 + i * 16 + (lane & 15);
      int offa = ar * 32 + ((kc ^ (ar & 3)) << 3);
      ah[i] = *(const fp16x8*)&sAh[offa];
      al[i] = *(const fp16x8*)&sAl[offa];
      int br = wc * 64 + i * 16 + (lane & 15);
      int offb = br * 32 + ((kc ^ (br & 3)) << 3);
      bh[i] = *(const fp16x8*)&sBh[offb];
      bl[i] = *(const fp16x8*)&sBl[offb];
    }
#pragma unroll
    for (int i = 0; i < 4; i++)
#pragma unroll
      for (int j = 0; j < 4; j++) {
        acc[i][j] = __builtin_amdgcn_mfma_f32_16x16x32_f16(ah[i], bh[j], acc[i][j], 0, 0, 0);
        acc[i][j] = __builtin_amdgcn_mfma_f32_16x16x32_f16(ah[i], bl[j], acc[i][j], 0, 0, 0);
        acc[i][j] = __builtin_amdgcn_mfma_f32_16x16x32_f16(al[i], bh[j], acc[i][j], 0, 0, 0);
      }
    __syncthreads();
  }
#pragma unroll
  for (int j = 0; j < 4; j++) {
    int col = n0 + wc * 64 + j * 16 + (lane & 15);
    float bc = bias[col];
#pragma unroll
    for (int i = 0; i < 4; i++)
#pragma unroll
      for (int q = 0; q < 4; q++) {
        int row = m0 + wr * 64 + i * 16 + ((lane >> 4) << 2) + q;
        float v = acc[i][j][q] + bc;
        v = v > 0.f ? v : 0.f;
        _Float16 h = (_Float16)v;
        size_t o = (size_t)row * N + col;
        Chi[o] = h;
        Clo[o] = (_Float16)(v - (float)h);
      }
  }
}

// ------- gate layer 3 FAST: fp32 logits + top2 + flag tier-2 + histogram ---
__global__ __launch_bounds__(256) void k_gate3_fast(
    const _Float16* __restrict__ h2h, const float* __restrict__ g3,
    const float* __restrict__ gb3,
    float* __restrict__ pout, int* __restrict__ idx0, int* __restrict__ idx1,
    float* __restrict__ w0, float* __restrict__ w1,
    int* __restrict__ amb2Cnt, int* __restrict__ amb2List,
    int* __restrict__ cnt0, int* __restrict__ cnt1) {
  __shared__ _Float16 shh[16 * 256];
  __shared__ float sg3[16][260];
  __shared__ float sgb[16];
  __shared__ float slog[16][17];
  __shared__ int sidx[16][2];
  __shared__ float swv[16][2];
  __shared__ int hc0[16], hc1[16];
  int tid = threadIdx.x;
  int tokBase = blockIdx.x * 16;
  if (tid < 16) { hc0[tid] = 0; hc1[tid] = 0; }
  {
    int t = tid >> 4, c = (tid & 15) * 16;
    size_t g = (size_t)(tokBase + t) * 256 + c;
    *(fp16x8*)&shh[t * 256 + c] = *(const fp16x8*)&h2h[g];
    *(fp16x8*)&shh[t * 256 + c + 8] = *(const fp16x8*)&h2h[g + 8];
  }
#pragma unroll
  for (int r = 0; r < 16; r++) {
    int j = r * 256 + tid;
    sg3[j & 15][j >> 4] = g3[j];
  }
  if (tid < 16) sgb[tid] = gb3[tid];
  __syncthreads();
  int t = tid >> 4, e = tid & 15;
  const _Float16* ph = &shh[t * 256];
  const float* pg = &sg3[e][0];
  float acc = 0.f;
  for (int k = 0; k < 256; k += 8) {
    fp16x8 hv = *(const fp16x8*)&ph[k];
    float4 ga = *(const float4*)&pg[k];
    float4 gb = *(const float4*)&pg[k + 4];
    acc = fmaf((float)hv[0], ga.x, acc);
    acc = fmaf((float)hv[1], ga.y, acc);
    acc = fmaf((float)hv[2], ga.z, acc);
    acc = fmaf((float)hv[3], ga.w, acc);
    acc = fmaf((float)hv[4], gb.x, acc);
    acc = fmaf((float)hv[5], gb.y, acc);
    acc = fmaf((float)hv[6], gb.z, acc);
    acc = fmaf((float)hv[7], gb.w, acc);
  }
  acc += sgb[e];
  slog[t][e] = acc;
  __syncthreads();
  if (e == 0) {
    float l[16];
#pragma unroll
    for (int i = 0; i < 16; i++) l[i] = slog[t][i];
    int i1 = 0;
    for (int i = 1; i < 16; i++) if (l[i] > l[i1]) i1 = i;
    int i2 = -1;
    for (int i = 0; i < 16; i++) { if (i == i1) continue; if (i2 < 0 || l[i] > l[i2]) i2 = i; }
    float l3 = -1e30f;
    for (int i = 0; i < 16; i++) { if (i == i1 || i == i2) continue; if (l[i] > l3) l3 = l[i]; }
    float lmax = l[i1];
    float S = 0.f;
    for (int i = 0; i < 16; i++) S += expf(l[i] - lmax);
    float p1 = 1.0f / S, p2 = expf(l[i2] - lmax) / S;
    float den = p1 + p2 + 1e-9f;
    sidx[t][0] = i1; sidx[t][1] = i2;
    swv[t][0] = p1 / den; swv[t][1] = p2 / den;
    atomicAdd(&hc0[i1], 1);
    atomicAdd(&hc1[i2], 1);
    if (l[i2] - l3 < TAU2) {
      int pos = atomicAdd(amb2Cnt, 1);
      if (pos < AMB2_CAP) amb2List[pos] = tokBase + t;
    }
  }
  __syncthreads();
  int i1 = sidx[t][0], i2 = sidx[t][1];
  float pv = (e == i1) ? swv[t][0] : ((e == i2) ? swv[t][1] : 0.f);
  pout[(size_t)(tokBase + t) * 16 + e] = pv;
  if (e == 0) {
    int tok = tokBase + t;
    idx0[tok] = i1; idx1[tok] = i2;
    w0[tok] = swv[t][0]; w1[tok] = swv[t][1];
  }
  if (tid < 16) {
    if (hc0[tid]) atomicAdd(&cnt0[tid], hc0[tid]);
    if (hc1[tid]) atomicAdd(&cnt1[tid], hc1[tid]);
  }
}

// ---------------- tier-2 gather: x -> xg hi/lo ----------------
__global__ __launch_bounds__(256) void k_gather2(
    const float* __restrict__ x, const int* __restrict__ cnt,
    const int* __restrict__ list,
    _Float16* __restrict__ xgh, _Float16* __restrict__ xgl) {
  int n = *cnt; if (n > AMB2_CAP) n = AMB2_CAP;
  int s = blockIdx.x * 8 + (threadIdx.x >> 5);
  if (s >= n) return;
  int tok = list[s];
  int c = (threadIdx.x & 31) * 8;
  const float4* p = (const float4*)&x[(size_t)tok * 256 + c];
  float4 a = p[0], b = p[1];
  float v[8] = {a.x, a.y, a.z, a.w, b.x, b.y, b.z, b.w};
  fp16x8 hv, lv;
#pragma unroll
  for (int j = 0; j < 8; j++) {
    _Float16 h = (_Float16)v[j];
    hv[j] = h;
    lv[j] = (_Float16)(v[j] - (float)h);
  }
  *(fp16x8*)&xgh[(size_t)s * 256 + c] = hv;
  *(fp16x8*)&xgl[(size_t)s * 256 + c] = lv;
}

// ------- tier-2 gate3 precise: fp64 logits, overwrite + hist delta --------
__global__ __launch_bounds__(256) void k_gate3_precise(
    const _Float16* __restrict__ h2ghi, const _Float16* __restrict__ h2glo,
    const float* __restrict__ g3, const float* __restrict__ gb3,
    const int* __restrict__ amb2Cnt, const int* __restrict__ amb2List,
    float* __restrict__ pout, int* __restrict__ idx0, int* __restrict__ idx1,
    float* __restrict__ w0, float* __restrict__ w1,
    int* __restrict__ amb3Cnt, int* __restrict__ amb3List,
    int* __restrict__ cnt0, int* __restrict__ cnt1) {
  __shared__ _Float16 shh[16 * 256], shl[16 * 256];
  __shared__ float sg3[16][260];
  __shared__ float sgb[16];
  __shared__ double slog[16][17];
  __shared__ int sidx[16][2];
  __shared__ float swv[16][2];
  int tid = threadIdx.x;
  int slotBase = blockIdx.x * 16;
  int n2 = *amb2Cnt; if (n2 > AMB2_CAP) n2 = AMB2_CAP;
  {
    int t = tid >> 4, c = (tid & 15) * 16;
    size_t g = (size_t)(slotBase + t) * 256 + c;
    *(fp16x8*)&shh[t * 256 + c] = *(const fp16x8*)&h2ghi[g];
    *(fp16x8*)&shh[t * 256 + c + 8] = *(const fp16x8*)&h2ghi[g + 8];
    *(fp16x8*)&shl[t * 256 + c] = *(const fp16x8*)&h2glo[g];
    *(fp16x8*)&shl[t * 256 + c + 8] = *(const fp16x8*)&h2glo[g + 8];
  }
#pragma unroll
  for (int r = 0; r < 16; r++) {
    int j = r * 256 + tid;
    sg3[j & 15][j >> 4] = g3[j];
  }
  if (tid < 16) sgb[tid] = gb3[tid];
  __syncthreads();
  int t = tid >> 4, e = tid & 15;
  int slot = slotBase + t;
  const _Float16* ph = &shh[t * 256];
  const _Float16* pl = &shl[t * 256];
  const float* pg = &sg3[e][0];
  double acc = 0.0;
  for (int k = 0; k < 256; k += 4) {
#pragma unroll
    for (int j = 0; j < 4; j++) {
      double a = (double)(float)ph[k + j] + (double)(float)pl[k + j];
      acc = fma(a, (double)pg[k + j], acc);
    }
  }
  acc += (double)sgb[e];
  slog[t][e] = acc;
  __syncthreads();
  if (e == 0 && slot < n2) {
    int tok = amb2List[slot];
    double l[16];
#pragma unroll
    for (int i = 0; i < 16; i++) l[i] = slog[t][i];
    int i1 = 0;
    for (int i = 1; i < 16; i++) if (l[i] > l[i1]) i1 = i;
    int i2 = -1;
    for (int i = 0; i < 16; i++) { if (i == i1) continue; if (i2 < 0 || l[i] > l[i2]) i2 = i; }
    double l3 = -1e300;
    for (int i = 0; i < 16; i++) { if (i == i1 || i == i2) continue; if (l[i] > l3) l3 = l[i]; }
    double lmax = l[i1];
    double S = 0.0;
    for (int i = 0; i < 16; i++) S += exp(l[i] - lmax);
    double p1 = 1.0 / S, p2 = exp(l[i2] - lmax) / S;
    double den = p1 + p2 + 1e-9;
    sidx[t][0] = i1; sidx[t][1] = i2;
    swv[t][0] = (float)(p1 / den); swv[t][1] = (float)(p2 / den);
    // histogram delta vs fast-path decision
    int o0 = idx0[tok], o1 = idx1[tok];
    if (i1 != o0) { atomicSub(&cnt0[o0], 1); atomicAdd(&cnt0[i1], 1); }
    if (i2 != o1) { atomicSub(&cnt1[o1], 1); atomicAdd(&cnt1[i2], 1); }
    if (l[i2] - l3 < TAU3) {
      int pos = atomicAdd(amb3Cnt, 1);
      if (pos < AMB3_CAP) amb3List[pos] = tok;
    }
  }
  __syncthreads();
  if (slot < n2) {
    int tok = amb2List[slot];
    int i1 = sidx[t][0], i2 = sidx[t][1];
    float pv = (e == i1) ? swv[t][0] : ((e == i2) ? swv[t][1] : 0.f);
    pout[(size_t)tok * 16 + e] = pv;
    if (e == 0) {
      idx0[tok] = i1; idx1[tok] = i2;
      w0[tok] = swv[t][0]; w1[tok] = swv[t][1];
    }
  }
}

// ---------------- tier-3 batched fp64: L1 ----------------
// grid (16, AMB3_CAP): block (panel j, token slot t); 256 thr = 64 out x 4 kparts
__global__ __launch_bounds__(256) void k_ref_l1(
    const float* __restrict__ x, const float* __restrict__ g1,
    const float* __restrict__ gb1,
    const int* __restrict__ cnt, const int* __restrict__ list,
    double* __restrict__ h1d) {
  int n = *cnt; if (n > AMB3_CAP) n = AMB3_CAP;
  int t = blockIdx.y;
  if (t >= n) return;
  __shared__ float sx[256];
  __shared__ double sred[4][64];
  int tid = threadIdx.x;
  int tok = list[t];
  sx[tid] = x[(size_t)tok * 256 + tid];
  __syncthreads();
  int o = tid & 63, p = tid >> 6;
  int out = blockIdx.x * 64 + o;
  double a = 0.0;
  const float* gp = g1 + (size_t)(p * 64) * 1024 + out;
  const float* xp = &sx[p * 64];
#pragma unroll 8
  for (int k = 0; k < 64; k++)
    a = fma((double)xp[k], (double)gp[(size_t)k * 1024], a);
  sred[p][o] = a;
  __syncthreads();
  if (p == 0) {
    double s = sred[0][o] + sred[1][o] + sred[2][o] + sred[3][o] + (double)gb1[out];
    h1d[(size_t)t * 1024 + out] = s > 0.0 ? s : 0.0;
  }
}

// ---------------- tier-3 batched fp64: L2 ----------------
// grid (4, AMB3_CAP): 512 thr = 64 out x 8 kparts
__global__ __launch_bounds__(512) void k_ref_l2(
    const double* __restrict__ h1d, const float* __restrict__ g2,
    const float* __restrict__ gb2,
    const int* __restrict__ cnt, double* __restrict__ h2d) {
  int n = *cnt; if (n > AMB3_CAP) n = AMB3_CAP;
  int t = blockIdx.y;
  if (t >= n) return;
  __shared__ double sh1[1024];
  __shared__ double sred[8][64];
  int tid = threadIdx.x;
  sh1[tid] = h1d[(size_t)t * 1024 + tid];
  sh1[512 + tid] = h1d[(size_t)t * 1024 + 512 + tid];
  __syncthreads();
  int o = tid & 63, p = tid >> 6;
  int out = blockIdx.x * 64 + o;
  double a = 0.0;
  const float* gp = g2 + (size_t)(p * 128) * 256 + out;
  const double* hp = &sh1[p * 128];
#pragma unroll 4
  for (int k = 0; k < 128; k++)
    a = fma(hp[k], (double)gp[(size_t)k * 256], a);
  sred[p][o] = a;
  __syncthreads();
  if (p == 0) {
    double s = sred[0][o] + sred[1][o] + sred[2][o] + sred[3][o] +
               sred[4][o] + sred[5][o] + sred[6][o] + sred[7][o] + (double)gb2[out];
    h2d[(size_t)t * 256 + out] = s > 0.0 ? s : 0.0;
  }
}

// ---------------- tier-3: L3 + decide + hist delta ----------------
__global__ __launch_bounds__(256) void k_ref_l3(
    const double* __restrict__ h2d, const float* __restrict__ g3,
    const float* __restrict__ gb3,
    const int* __restrict__ cnt, const int* __restrict__ list,
    float* __restrict__ pout, int* __restrict__ idx0, int* __restrict__ idx1,
    float* __restrict__ w0, float* __restrict__ w1,
    int* __restrict__ cnt0, int* __restrict__ cnt1) {
  int n = *cnt; if (n > AMB3_CAP) n = AMB3_CAP;
  int t = blockIdx.x;
  if (t >= n) return;
  __shared__ double sh2[256];
  __shared__ double sl16[16][17];
  __shared__ int sidx[2];
  __shared__ float swv[2];
  int tid = threadIdx.x;
  int tok = list[t];
  sh2[tid] = h2d[(size_t)t * 256 + tid];
  __syncthreads();
  {
    int o = tid & 15, pp = tid >> 4;
    double a = 0.0;
#pragma unroll
    for (int k = pp * 16; k < pp * 16 + 16; k++)
      a = fma(sh2[k], (double)g3[(size_t)k * 16 + o], a);
    sl16[pp][o] = a;
  }
  __syncthreads();
  if (tid == 0) {
    double l[16];
    for (int o = 0; o < 16; o++) {
      double a = (double)gb3[o];
      for (int p = 0; p < 16; p++) a += sl16[p][o];
      l[o] = a;
    }
    int i1 = 0;
    for (int i = 1; i < 16; i++) if (l[i] > l[i1]) i1 = i;
    int i2 = -1;
    for (int i = 0; i < 16; i++) { if (i == i1) continue; if (i2 < 0 || l[i] > l[i2]) i2 = i; }
    double lmax = l[i1];
    double S = 0.0;
    for (int i = 0; i < 16; i++) S += exp(l[i] - lmax);
    double p1 = 1.0 / S, p2 = exp(l[i2] - lmax) / S;
    double den = p1 + p2 + 1e-9;
    float fw0 = (float)(p1 / den), fw1 = (float)(p2 / den);
    int o0 = idx0[tok], o1 = idx1[tok];
    if (i1 != o0) { atomicSub(&cnt0[o0], 1); atomicAdd(&cnt0[i1], 1); }
    if (i2 != o1) { atomicSub(&cnt1[o1], 1); atomicAdd(&cnt1[i2], 1); }
    sidx[0] = i1; sidx[1] = i2;
    swv[0] = fw0; swv[1] = fw1;
    idx0[tok] = i1; idx1[tok] = i2;
    w0[tok] = fw0; w1[tok] = fw1;
  }
  __syncthreads();
  if (tid < 16) {
    float pv = (tid == sidx[0]) ? swv[0] : ((tid == sidx[1]) ? swv[1] : 0.f);
    pout[(size_t)tok * 16 + tid] = pv;
  }
}

// ---------------- offsets / scatter ----------------
__global__ void k_offsets(const int* __restrict__ cnt0, const int* __restrict__ cnt1,
                          int* off0, int* off1, int* cur0, int* cur1,
                          int* dExp0, int* dRow0, int* dExp1, int* dRow1, int* nTiles) {
  if (threadIdx.x == 0) {
    int tot = 0, nt = 0;
    for (int e = 0; e < 16; e++) {
      off0[e] = tot; cur0[e] = 0;
      int tiles = (cnt0[e] + 127) >> 7;
      for (int ti = 0; ti < tiles; ti++) { dExp0[nt] = e; dRow0[nt] = tot + ti * 128; nt++; }
      tot += tiles * 128;
    }
    nTiles[0] = nt;
    tot = 0; nt = 0;
    for (int e = 0; e < 16; e++) {
      off1[e] = tot; cur1[e] = 0;
      int tiles = (cnt1[e] + 127) >> 7;
      for (int ti = 0; ti < tiles; ti++) { dExp1[nt] = e; dRow1[nt] = tot + ti * 128; nt++; }
      tot += tiles * 128;
    }
    nTiles[1] = nt;
  }
}

__global__ __launch_bounds__(256) void k_scatter(
    const int* __restrict__ idx0, const int* __restrict__ idx1,
    const float* __restrict__ w0, const float* __restrict__ w1,
    const int* __restrict__ off0, const int* __restrict__ off1,
    int* cur0, int* cur1,
    int* __restrict__ tok0, float* __restrict__ wl0,
    int* __restrict__ tok1, float* __restrict__ wl1) {
  __shared__ int c0[16], c1[16], b0[16], b1[16];
  int tid = threadIdx.x;
  if (tid < 16) { c0[tid] = 0; c1[tid] = 0; }
  __syncthreads();
  int b = blockIdx.x * 256 + tid;
  int e0 = idx0[b], e1 = idx1[b];
  int r0 = atomicAdd(&c0[e0], 1);
  int r1 = atomicAdd(&c1[e1], 1);
  __syncthreads();
  if (tid < 16) { b0[tid] = atomicAdd(&cur0[tid], c0[tid]); b1[tid] = atomicAdd(&cur1[tid], c1[tid]); }
  __syncthreads();
  int p0 = off0[e0] + b0[e0] + r0;
  tok0[p0] = b; wl0[p0] = w0[b];
  int p1 = off1[e1] + b1[e1] + r1;
  tok1[p1] = b; wl1[p1] = w1[b];
}

// ---------------- fused 2-layer expert MLP, grouped by expert --------------
template <int PASSB>
__global__ __launch_bounds__(512) void k_expert(
    const _Float16* __restrict__ xhi, const float* __restrict__ bias,
    const _Float16* __restrict__ W1T, const float* __restrict__ b1,
    const _Float16* __restrict__ W2T, const float* __restrict__ b2,
    const int* __restrict__ dExp, const int* __restrict__ dRow,
    const int* __restrict__ nT,
    const int* __restrict__ tokL, const float* __restrict__ wL,
    float* __restrict__ y) {
  __shared__ _Float16 sA[128 * 64];
  __shared__ _Float16 sB[256 * 64];
  __shared__ _Float16 sHE[128 * 264];
  __shared__ int sTok[128];
  __shared__ float sW[128];
  int tid = threadIdx.x, lane = tid & 63, wave = tid >> 6;
  int wr = wave >> 2, wc = wave & 3;
  f32x4_t zero4 = {0.f, 0.f, 0.f, 0.f};
  int nt = *nT;
  for (int t = blockIdx.x; t < nt; t += gridDim.x) {
    int e = dExp[t], rowOff = dRow[t];
    if (tid < 128) { sTok[tid] = tokL[rowOff + tid]; sW[tid] = wL[rowOff + tid]; }
    __syncthreads();
    f32x4_t acc[4][4];
#pragma unroll
    for (int i = 0; i < 4; i++)
#pragma unroll
      for (int j = 0; j < 4; j++) acc[i][j] = zero4;
    const _Float16* W1e = W1T + (size_t)e * 65536;
    const _Float16* W2e = W2T + (size_t)e * 65536;
    const float* be = bias + e * 256;
    for (int k0 = 0; k0 < 256; k0 += 64) {
#pragma unroll
      for (int r = 0; r < 2; r++) {
        int idx = r * 512 + tid;
        int row = idx >> 3, ch = idx & 7, gch = ch ^ (row & 7);
        int tok = sTok[row];
        int tk = tok < 0 ? 0 : tok;
        fp16x8 v = *(const fp16x8*)&xhi[(size_t)tk * 256 + k0 + gch * 8];
        const float* bp = &be[k0 + gch * 8];
#pragma unroll
        for (int j = 0; j < 8; j++) v[j] = (_Float16)((float)v[j] + bp[j]);
        *(fp16x8*)&sA[row * 64 + ch * 8] = v;
      }
#pragma unroll
      for (int r = 0; r < 4; r++) {
        int idx = r * 512 + tid;
        int row = idx >> 3, ch = idx & 7, gch = ch ^ (row & 7);
        *(fp16x8*)&sB[row * 64 + ch * 8] =
            *(const fp16x8*)&W1e[(size_t)row * 256 + k0 + gch * 8];
      }
      __syncthreads();
#pragma unroll
      for (int kk = 0; kk < 2; kk++) {
        fp16x8 a[4], bf[4];
        int kcg = kk * 4 + (lane >> 4);
#pragma unroll
        for (int i = 0; i < 4; i++) {
          int ar = wr * 64 + i * 16 + (lane & 15);
          a[i] = *(const fp16x8*)&sA[ar * 64 + (kcg ^ (ar & 7)) * 8];
          int br = wc * 64 + i * 16 + (lane & 15);
          bf[i] = *(const fp16x8*)&sB[br * 64 + (kcg ^ (br & 7)) * 8];
        }
#pragma unroll
        for (int i = 0; i < 4; i++)
#pragma unroll
          for (int j = 0; j < 4; j++)
            acc[i][j] = __builtin_amdgcn_mfma_f32_16x16x32_f16(a[i], bf[j], acc[i][j], 0, 0, 0);
      }
      __syncthreads();
    }
#pragma unroll
    for (int j = 0; j < 4; j++) {
      int col = wc * 64 + j * 16 + (lane & 15);
      float bb = b1[e * 256 + col];
#pragma unroll
      for (int i = 0; i < 4; i++)
#pragma unroll
        for (int q = 0; q < 4; q++) {
          int row = wr * 64 + i * 16 + ((lane >> 4) << 2) + q;
          float v = acc[i][j][q] + bb;
          v = v > 0.f ? v : 0.f;
          sHE[row * 264 + col] = (_Float16)v;
        }
    }
#pragma unroll
    for (int i = 0; i < 4; i++)
#pragma unroll
      for (int j = 0; j < 4; j++) acc[i][j] = zero4;
    __syncthreads();
    for (int k0 = 0; k0 < 256; k0 += 64) {
#pragma unroll
      for (int r = 0; r < 4; r++) {
        int idx = r * 512 + tid;
        int row = idx >> 3, ch = idx & 7, gch = ch ^ (row & 7);
        *(fp16x8*)&sB[row * 64 + ch * 8] =
            *(const fp16x8*)&W2e[(size_t)row * 256 + k0 + gch * 8];
      }
      __syncthreads();
#pragma unroll
      for (int kk = 0; kk < 2; kk++) {
        fp16x8 a[4], bf[4];
        int kcg = kk * 4 + (lane >> 4);
#pragma unroll
        for (int i = 0; i < 4; i++) {
          int ar = wr * 64 + i * 16 + (lane & 15);
          a[i] = *(const fp16x8*)&sHE[ar * 264 + k0 + kk * 32 + (lane >> 4) * 8];
          int br = wc * 64 + i * 16 + (lane & 15);
          bf[i] = *(const fp16x8*)&sB[br * 64 + (kcg ^ (br & 7)) * 8];
        }
#pragma unroll
        for (int i = 0; i < 4; i++)
#pragma unroll
          for (int j = 0; j < 4; j++)
            acc[i][j] = __builtin_amdgcn_mfma_f32_16x16x32_f16(a[i], bf[j], acc[i][j], 0, 0, 0);
      }
      __syncthreads();
    }
#pragma unroll
    for (int j = 0; j < 4; j++) {
      int col = wc * 64 + j * 16 + (lane & 15);
      float bb = b2[e * 256 + col];
#pragma unroll
      for (int i = 0; i < 4; i++)
#pragma unroll
        for (int q = 0; q < 4; q++) {
          int row = wr * 64 + i * 16 + ((lane >> 4) << 2) + q;
          int tok = sTok[row];
          if (tok >= 0) {
            float v = (acc[i][j][q] + bb) * sW[row];
            size_t o = (size_t)tok * 256 + col;
            if (PASSB) y[o] += v; else y[o] = v;
          }
        }
    }
    __syncthreads();
  }
}

// ---------------- host-side orchestration ----------------
extern "C" void kernel_launch(void* const* d_in, const int* in_sizes, int n_in,
                              void* d_out, int out_size, void* d_ws, size_t ws_size,
                              hipStream_t stream) {
  const float* x   = (const float*)d_in[0];
  const float* bias= (const float*)d_in[1];
  const float* W1  = (const float*)d_in[2];
  const float* b1  = (const float*)d_in[3];
  const float* W2  = (const float*)d_in[4];
  const float* b2  = (const float*)d_in[5];
  const float* g1  = (const float*)d_in[6];
  const float* gb1 = (const float*)d_in[7];
  const float* g2  = (const float*)d_in[8];
  const float* gb2 = (const float*)d_in[9];
  const float* g3  = (const float*)d_in[10];
  const float* gb3 = (const float*)d_in[11];
  float* y    = (float*)d_out;
  float* pout = y + (size_t)BTOK * 256;

  char* w = (char*)d_ws;
  auto alloc = [&](size_t bytes) -> char* {
    char* p = w;
    w += (bytes + 255) & ~(size_t)255;
    return p;
  };
  _Float16* xhi  = (_Float16*)alloc((size_t)BTOK * 256 * 2);
  _Float16* h2h  = (_Float16*)alloc((size_t)BTOK * 256 * 2);
  _Float16* g1Th = (_Float16*)alloc((size_t)256 * 1024 * 2);
  _Float16* g1Tl = (_Float16*)alloc((size_t)256 * 1024 * 2);
  _Float16* g2Th = (_Float16*)alloc((size_t)256 * 1024 * 2);
  _Float16* g2Tl = (_Float16*)alloc((size_t)256 * 1024 * 2);
  _Float16* W1T  = (_Float16*)alloc((size_t)16 * 65536 * 2);
  _Float16* W2T  = (_Float16*)alloc((size_t)16 * 65536 * 2);
  int*   idx0 = (int*)alloc((size_t)BTOK * 4);
  int*   idx1 = (int*)alloc((size_t)BTOK * 4);
  float* w0a  = (float*)alloc((size_t)BTOK * 4);
  float* w1a  = (float*)alloc((size_t)BTOK * 4);
  int*   ctrl = (int*)alloc(4096);
  int*   amb2List = (int*)alloc((size_t)AMB2_CAP * 4);
  int*   amb3List = (int*)alloc((size_t)AMB3_CAP * 4);
  int*   dExp0 = (int*)alloc(544 * 4);
  int*   dRow0 = (int*)alloc(544 * 4);
  int*   dExp1 = (int*)alloc(544 * 4);
  int*   dRow1 = (int*)alloc(544 * 4);
  const int LCAP = BTOK + 16 * 128;
  int*   tok0 = (int*)alloc((size_t)LCAP * 4);
  float* wl0  = (float*)alloc((size_t)LCAP * 4);
  int*   tok1 = (int*)alloc((size_t)LCAP * 4);
  float* wl1  = (float*)alloc((size_t)LCAP * 4);
  // tier-2 buffers
  _Float16* xgh  = (_Float16*)alloc((size_t)AMB2_CAP * 256 * 2);
  _Float16* xgl  = (_Float16*)alloc((size_t)AMB2_CAP * 256 * 2);
  _Float16* h1gh = (_Float16*)alloc((size_t)AMB2_CAP * 1024 * 2);
  _Float16* h1gl = (_Float16*)alloc((size_t)AMB2_CAP * 1024 * 2);
  _Float16* h2gh = (_Float16*)alloc((size_t)AMB2_CAP * 256 * 2);
  _Float16* h2gl = (_Float16*)alloc((size_t)AMB2_CAP * 256 * 2);
  // tier-3 buffers (fp64 intermediates)
  double* h1d = (double*)alloc((size_t)AMB3_CAP * 1024 * 8);
  double* h2d = (double*)alloc((size_t)AMB3_CAP * 256 * 8);

  size_t used = (size_t)(w - (char*)d_ws);
  size_t remain = ws_size > used ? ws_size - used : 0;
  int CG = 1;
  while (CG < 64 && (size_t)(BTOK / CG) * 1024 * 2 + 1024 > remain) CG <<= 1;
  int MC = BTOK / CG;
  _Float16* h1h = (_Float16*)alloc((size_t)MC * 1024 * 2);

  int* cnt0 = ctrl + 0;  int* cnt1 = ctrl + 16;
  int* off0 = ctrl + 32; int* off1 = ctrl + 48;
  int* cur0 = ctrl + 64; int* cur1 = ctrl + 80;
  int* nTiles = ctrl + 96;
  int* amb2Cnt = ctrl + 112;
  int* amb3Cnt = ctrl + 116;

  hipMemsetAsync(ctrl, 0, 4096, stream);
  hipMemsetAsync(tok0, 0xFF, (size_t)LCAP * 4, stream);
  hipMemsetAsync(tok1, 0xFF, (size_t)LCAP * 4, stream);

  dim3 tb(256);
  k_transpose_cvt<<<dim3(32, 8, 1), tb, 0, stream>>>(g1, g1Th, g1Tl, 256, 1024);
  k_transpose_cvt<<<dim3(8, 32, 1), tb, 0, stream>>>(g2, g2Th, g2Tl, 1024, 256);
  k_transpose_cvt<<<dim3(8, 8, 16), tb, 0, stream>>>(W1, W1T, nullptr, 256, 256);
  k_transpose_cvt<<<dim3(8, 8, 16), tb, 0, stream>>>(W2, W2T, nullptr, 256, 256);
  k_xcvt_hi<<<(BTOK * 256 / 8 + 255) / 256, tb, 0, stream>>>(x, xhi, BTOK * 256 / 8);

  // ---- fast gate (single f16) ----
  for (int c = 0; c < CG; c++) {
    const _Float16* xh = xhi + (size_t)c * MC * 256;
    k_gemm_f16<<<dim3(8, MC / 128), tb, 0, stream>>>(xh, g1Th, gb1, h1h, MC, 1024, 256);
    k_gemm_f16<<<dim3(2, MC / 128), tb, 0, stream>>>(h1h, g2Th, gb2,
                                                     h2h + (size_t)c * MC * 256, MC, 256, 1024);
  }
  k_gate3_fast<<<BTOK / 16, tb, 0, stream>>>(h2h, g3, gb3, pout, idx0, idx1,
                                             w0a, w1a, amb2Cnt, amb2List, cnt0, cnt1);

  // ---- tier-2: split-f16 precise gate on near-tie tokens ----
  k_gather2<<<AMB2_CAP / 8, tb, 0, stream>>>(x, amb2Cnt, amb2List, xgh, xgl);
  k_gemm_split<<<dim3(8, AMB2_CAP / 128), tb, 0, stream>>>(
      xgh, xgl, g1Th, g1Tl, gb1, h1gh, h1gl, AMB2_CAP, 1024, 256, amb2Cnt);
  k_gemm_split<<<dim3(2, AMB2_CAP / 128), tb, 0, stream>>>(
      h1gh, h1gl, g2Th, g2Tl, gb2, h2gh, h2gl, AMB2_CAP, 256, 1024, amb2Cnt);
  k_gate3_precise<<<AMB2_CAP / 16, tb, 0, stream>>>(
      h2gh, h2gl, g3, gb3, amb2Cnt, amb2List, pout, idx0, idx1, w0a, w1a,
      amb3Cnt, amb3List, cnt0, cnt1);

  // ---- tier-3: batched parallel fp64 ----
  k_ref_l1<<<dim3(16, AMB3_CAP), tb, 0, stream>>>(x, g1, gb1, amb3Cnt, amb3List, h1d);
  k_ref_l2<<<dim3(4, AMB3_CAP), 512, 0, stream>>>(h1d, g2, gb2, amb3Cnt, h2d);
  k_ref_l3<<<AMB3_CAP, tb, 0, stream>>>(h2d, g3, gb3, amb3Cnt, amb3List,
                                        pout, idx0, idx1, w0a, w1a, cnt0, cnt1);

  // ---- expert buckets + fused expert MLP ----
  k_offsets<<<1, 64, 0, stream>>>(cnt0, cnt1, off0, off1, cur0, cur1,
                                  dExp0, dRow0, dExp1, dRow1, nTiles);
  k_scatter<<<BTOK / 256, tb, 0, stream>>>(idx0, idx1, w0a, w1a, off0, off1,
                                           cur0, cur1, tok0, wl0, tok1, wl1);
  k_expert<0><<<528, 512, 0, stream>>>(xhi, bias, W1T, b1, W2T, b2,
                                       dExp0, dRow0, nTiles + 0, tok0, wl0, y);
  k_expert<1><<<528, 512, 0, stream>>>(xhi, bias, W1T, b1, W2T, b2,
                                       dExp1, dRow1, nTiles + 1, tok1, wl1, y);
}